// Round 2
// baseline (18551.649 us; speedup 1.0000x reference)
//
#include <hip/hip_runtime.h>
#include <math.h>

#define B_ 32
#define L_ 512
#define S_ 37
#define STATIC_ 8
#define D_ 768
#define DI_ 1536
#define N_ 16
#define KCONV_ 4
#define DTR_ 48
#define NL_ 4
#define V_ 32
#define ROWS_ (B_*L_)      // 16384
#define CB_ 8              // batch chunk
#define CROWS_ (CB_*L_)    // 4096 rows per chunk
#define NCH_ (B_/CB_)      // 4 chunks

__device__ __forceinline__ float silu_(float x) { return x / (1.f + __expf(-x)); }

__device__ __forceinline__ void block_reduce2_(float& a, float& b, float* sbuf) {
    #pragma unroll
    for (int off = 32; off > 0; off >>= 1) {
        a += __shfl_down(a, off, 64);
        b += __shfl_down(b, off, 64);
    }
    int lane = threadIdx.x & 63, wid = threadIdx.x >> 6;
    if (lane == 0) { sbuf[wid] = a; sbuf[4 + wid] = b; }
    __syncthreads();
    a = sbuf[0] + sbuf[1] + sbuf[2] + sbuf[3];
    b = sbuf[4] + sbuf[5] + sbuf[6] + sbuf[7];
}

// ---------------- embed + static + layernorm, one block per (b,l) row ----------------
__global__ __launch_bounds__(256) void embed_ln_kernel(
    const float* __restrict__ x, const int* __restrict__ mask,
    const float* __restrict__ stat, const float* __restrict__ emb_w,
    const float* __restrict__ emb_b, const float* __restrict__ static_w,
    const float* __restrict__ static_b, const float* __restrict__ ln_w,
    const float* __restrict__ ln_b, float* __restrict__ h)
{
    int row = blockIdx.x;              // b*L + l
    int b = row / L_;
    int tid = threadIdx.x;
    __shared__ float feats[2 * S_];    // 74
    __shared__ float st[STATIC_];
    __shared__ float sbuf[8];
    if (tid < S_)            feats[tid] = x[(size_t)row * S_ + tid];
    else if (tid < 2 * S_)   feats[tid] = (float)mask[(size_t)row * S_ + (tid - S_)];
    if (tid >= 128 && tid < 128 + STATIC_) st[tid - 128] = stat[b * STATIC_ + (tid - 128)];
    __syncthreads();

    float v[3];
    float sum = 0.f, sumsq = 0.f;
    #pragma unroll
    for (int j = 0; j < 3; j++) {
        int d = tid + 256 * j;
        float acc = emb_b[d] + static_b[d];
        const float* wr = emb_w + (size_t)d * (2 * S_);
        #pragma unroll
        for (int f = 0; f < 2 * S_; f++) acc += feats[f] * wr[f];
        const float* sw = static_w + (size_t)d * STATIC_;
        #pragma unroll
        for (int s = 0; s < STATIC_; s++) acc += st[s] * sw[s];
        v[j] = acc;
        sum += acc; sumsq += acc * acc;
    }
    block_reduce2_(sum, sumsq, sbuf);
    float mu = sum * (1.f / D_);
    float var = sumsq * (1.f / D_) - mu * mu;
    float rstd = rsqrtf(var + 1e-5f);
    #pragma unroll
    for (int j = 0; j < 3; j++) {
        int d = tid + 256 * j;
        h[(size_t)row * D_ + d] = (v[j] - mu) * rstd * ln_w[d] + ln_b[d];
    }
}

// ---------------- rmsnorm, one block per row ----------------
__global__ __launch_bounds__(256) void rmsnorm_kernel(
    const float* __restrict__ h, const float* __restrict__ w, float* __restrict__ out)
{
    int row = blockIdx.x;
    int tid = threadIdx.x;
    __shared__ float sbuf[8];
    float v[3];
    float ss = 0.f, dummy = 0.f;
    #pragma unroll
    for (int j = 0; j < 3; j++) {
        v[j] = h[(size_t)row * D_ + tid + 256 * j];
        ss += v[j] * v[j];
    }
    block_reduce2_(ss, dummy, sbuf);
    float rstd = rsqrtf(ss * (1.f / D_) + 1e-5f);
    #pragma unroll
    for (int j = 0; j < 3; j++) {
        int d = tid + 256 * j;
        out[(size_t)row * D_ + d] = v[j] * rstd * w[d];
    }
}

// ---------------- generic fp32 GEMM: C[M,N] = A[M,K] @ W[N,K]^T (+ addsrc) ----------------
__global__ __launch_bounds__(256) void gemm_tn_kernel(
    const float* __restrict__ A, const float* __restrict__ W,
    const float* __restrict__ addsrc, float* __restrict__ C,
    int M, int N, int Kd)
{
    __shared__ float As[16][68];
    __shared__ float Ws[16][68];
    int tid = threadIdx.x;
    int tx = tid & 15, ty = tid >> 4;
    int m0 = blockIdx.y * 64, n0 = blockIdx.x * 64;
    float acc[4][4] = {};

    for (int kt = 0; kt < Kd; kt += 16) {
        #pragma unroll
        for (int i = 0; i < 4; i++) {
            int lin = tid + 256 * i;
            int r = lin >> 4, kk = lin & 15;
            As[kk][r] = A[(size_t)(m0 + r) * Kd + kt + kk];
            int n = n0 + r;
            Ws[kk][r] = (n < N) ? W[(size_t)n * Kd + kt + kk] : 0.f;
        }
        __syncthreads();
        #pragma unroll
        for (int k = 0; k < 16; k++) {
            float a0 = As[k][ty * 4 + 0], a1 = As[k][ty * 4 + 1];
            float a2 = As[k][ty * 4 + 2], a3 = As[k][ty * 4 + 3];
            float b0 = Ws[k][tx * 4 + 0], b1 = Ws[k][tx * 4 + 1];
            float b2 = Ws[k][tx * 4 + 2], b3 = Ws[k][tx * 4 + 3];
            acc[0][0] += a0 * b0; acc[0][1] += a0 * b1; acc[0][2] += a0 * b2; acc[0][3] += a0 * b3;
            acc[1][0] += a1 * b0; acc[1][1] += a1 * b1; acc[1][2] += a1 * b2; acc[1][3] += a1 * b3;
            acc[2][0] += a2 * b0; acc[2][1] += a2 * b1; acc[2][2] += a2 * b2; acc[2][3] += a2 * b3;
            acc[3][0] += a3 * b0; acc[3][1] += a3 * b1; acc[3][2] += a3 * b2; acc[3][3] += a3 * b3;
        }
        __syncthreads();
    }
    #pragma unroll
    for (int i = 0; i < 4; i++) {
        #pragma unroll
        for (int j = 0; j < 4; j++) {
            int m = m0 + ty * 4 + i, n = n0 + tx * 4 + j;
            if (n < N) {
                float vv = acc[i][j];
                if (addsrc) vv += addsrc[(size_t)m * N + n];
                C[(size_t)m * N + n] = vv;
            }
        }
    }
}

// ---------------- causal depthwise conv (K=4) + silu, per chunk ----------------
__global__ __launch_bounds__(256) void conv_silu_kernel(
    const float* __restrict__ xz, const float* __restrict__ cw,
    const float* __restrict__ cb, float* __restrict__ xc)
{
    int idx = blockIdx.x * 256 + threadIdx.x;   // over CROWS_*DI_
    int d = idx % DI_;
    int row = idx / DI_;
    int t = row % L_;
    float w0 = cw[d * 4 + 0], w1 = cw[d * 4 + 1], w2 = cw[d * 4 + 2], w3 = cw[d * 4 + 3];
    float acc = cb[d];
    if (t >= 3) acc += w0 * xz[(size_t)(row - 3) * (2 * DI_) + d];
    if (t >= 2) acc += w1 * xz[(size_t)(row - 2) * (2 * DI_) + d];
    if (t >= 1) acc += w2 * xz[(size_t)(row - 1) * (2 * DI_) + d];
    acc += w3 * xz[(size_t)row * (2 * DI_) + d];
    xc[idx] = silu_(acc);
}

// ---------------- dt = softplus(dt_r @ dt_proj_w^T + dt_proj_b) ----------------
__global__ __launch_bounds__(256) void dt_kernel(
    const float* __restrict__ proj, const float* __restrict__ dtw,
    const float* __restrict__ dtb, float* __restrict__ dt)
{
    int idx = blockIdx.x * 256 + threadIdx.x;   // CROWS_*DI_
    int d = idx % DI_;
    int row = idx / DI_;
    const float* pr = proj + (size_t)row * (DTR_ + 2 * N_);
    const float* wr = dtw + (size_t)d * DTR_;
    float acc = dtb[d];
    #pragma unroll
    for (int r = 0; r < DTR_; r++) acc += pr[r] * wr[r];
    dt[idx] = fmaxf(acc, 0.f) + log1pf(__expf(-fabsf(acc)));
}

// ---------------- selective scan: thread per (b,d), 16 states in registers ----------------
__global__ __launch_bounds__(256) void scan_kernel(
    const float* __restrict__ dt, const float* __restrict__ xc,
    const float* __restrict__ proj, const float* __restrict__ A_log,
    float* __restrict__ y)
{
    int b = blockIdx.y;                        // within chunk
    int d = blockIdx.x * 256 + threadIdx.x;    // gridDim.x = 6
    float A[N_];
    #pragma unroll
    for (int n = 0; n < N_; n++) A[n] = -__expf(A_log[(size_t)d * N_ + n]);
    float h[N_];
    #pragma unroll
    for (int n = 0; n < N_; n++) h[n] = 0.f;

    for (int t = 0; t < L_; t++) {
        size_t row = (size_t)b * L_ + t;
        float dtv = dt[row * DI_ + d];
        float uv  = xc[row * DI_ + d];
        const float4* pBC = (const float4*)(proj + row * (DTR_ + 2 * N_) + DTR_);
        float4 Bv[4], Cv[4];
        #pragma unroll
        for (int q = 0; q < 4; q++) Bv[q] = pBC[q];
        #pragma unroll
        for (int q = 0; q < 4; q++) Cv[q] = pBC[4 + q];
        float du = dtv * uv;
        float yv = 0.f;
        const float* Bs = (const float*)Bv;
        const float* Cs = (const float*)Cv;
        #pragma unroll
        for (int n = 0; n < N_; n++) {
            float dA = __expf(dtv * A[n]);
            h[n] = dA * h[n] + du * Bs[n];
            yv += h[n] * Cs[n];
        }
        y[row * DI_ + d] = yv;
    }
}

// ---------------- y = (y + D*xc) * silu(z) ----------------
__global__ __launch_bounds__(256) void ypost_kernel(
    const float* __restrict__ xc, const float* __restrict__ xz,
    const float* __restrict__ Dp, float* __restrict__ y)
{
    int idx = blockIdx.x * 256 + threadIdx.x;   // CROWS_*DI_
    int d = idx % DI_;
    int row = idx / DI_;
    float z = xz[(size_t)row * (2 * DI_) + DI_ + d];
    y[idx] = (y[idx] + Dp[d] * xc[idx]) * silu_(z);
}

extern "C" void kernel_launch(void* const* d_in, const int* in_sizes, int n_in,
                              void* d_out, int out_size, void* d_ws, size_t ws_size,
                              hipStream_t stream) {
    const float* x        = (const float*)d_in[0];
    const float* stat     = (const float*)d_in[1];
    const int*   mask     = (const int*)d_in[3];
    const float* emb_w    = (const float*)d_in[5];
    const float* emb_b    = (const float*)d_in[6];
    const float* static_w = (const float*)d_in[7];
    const float* static_b = (const float*)d_in[8];
    const float* ln_w     = (const float*)d_in[9];
    const float* ln_b     = (const float*)d_in[10];
    const float* norm_w   = (const float*)d_in[11];
    const float* in_proj_w  = (const float*)d_in[12];
    const float* conv_w   = (const float*)d_in[13];
    const float* conv_b   = (const float*)d_in[14];
    const float* x_proj_w = (const float*)d_in[15];
    const float* dt_proj_w= (const float*)d_in[16];
    const float* dt_proj_b= (const float*)d_in[17];
    const float* A_log    = (const float*)d_in[18];
    const float* D_param  = (const float*)d_in[19];
    const float* out_proj_w = (const float*)d_in[20];
    const float* norm_f_w = (const float*)d_in[21];
    const float* lm_head_w= (const float*)d_in[22];
    float* out = (float*)d_out;

    // workspace layout (floats) — transients are per-chunk (CROWS_ rows)
    // total ≈ 47.5M floats ≈ 190 MB
    float* ws   = (float*)d_ws;
    float* h    = ws;                                     // ROWS_*D_      = 12.58M
    float* hn   = h    + (size_t)ROWS_ * D_;              // CROWS_*D_     =  3.15M
    float* xz   = hn   + (size_t)CROWS_ * D_;             // CROWS_*2DI_   = 12.58M
    float* xc   = xz   + (size_t)CROWS_ * 2 * DI_;        // CROWS_*DI_    =  6.29M
    float* proj = xc   + (size_t)CROWS_ * DI_;            // CROWS_*80     =  0.33M
    float* dtb  = proj + (size_t)CROWS_ * (DTR_ + 2 * N_);// CROWS_*DI_    =  6.29M
    float* y    = dtb  + (size_t)CROWS_ * DI_;            // CROWS_*DI_    =  6.29M

    embed_ln_kernel<<<ROWS_, 256, 0, stream>>>(x, mask, stat, emb_w, emb_b,
                                               static_w, static_b, ln_w, ln_b, h);

    const int EW = CROWS_ * DI_ / 256;   // 24576 blocks, elementwise over (CROWS_, DI_)
    for (int l = 0; l < NL_; l++) {
        for (int c = 0; c < NCH_; c++) {
            float* hc = h + (size_t)c * CROWS_ * D_;

            rmsnorm_kernel<<<CROWS_, 256, 0, stream>>>(hc, norm_w + (size_t)l * D_, hn);

            dim3 g_in((2 * DI_) / 64, CROWS_ / 64);
            gemm_tn_kernel<<<g_in, 256, 0, stream>>>(hn, in_proj_w + (size_t)l * 2 * DI_ * D_,
                                                     nullptr, xz, CROWS_, 2 * DI_, D_);

            conv_silu_kernel<<<EW, 256, 0, stream>>>(xz, conv_w + (size_t)l * DI_ * KCONV_,
                                                     conv_b + (size_t)l * DI_, xc);

            dim3 g_xp((DTR_ + 2 * N_ + 63) / 64, CROWS_ / 64);
            gemm_tn_kernel<<<g_xp, 256, 0, stream>>>(xc, x_proj_w + (size_t)l * (DTR_ + 2 * N_) * DI_,
                                                     nullptr, proj, CROWS_, DTR_ + 2 * N_, DI_);

            dt_kernel<<<EW, 256, 0, stream>>>(proj, dt_proj_w + (size_t)l * DI_ * DTR_,
                                              dt_proj_b + (size_t)l * DI_, dtb);

            dim3 g_scan(DI_ / 256, CB_);
            scan_kernel<<<g_scan, 256, 0, stream>>>(dtb, xc, proj,
                                                    A_log + (size_t)l * DI_ * N_, y);

            ypost_kernel<<<EW, 256, 0, stream>>>(xc, xz, D_param + (size_t)l * DI_, y);

            dim3 g_out(D_ / 64, CROWS_ / 64);
            gemm_tn_kernel<<<g_out, 256, 0, stream>>>(y, out_proj_w + (size_t)l * D_ * DI_,
                                                      hc, hc, CROWS_, D_, DI_);
        }
    }

    for (int c = 0; c < NCH_; c++) {
        float* hc = h + (size_t)c * CROWS_ * D_;
        rmsnorm_kernel<<<CROWS_, 256, 0, stream>>>(hc, norm_f_w, hn);
        dim3 g_lm((V_ + 63) / 64, CROWS_ / 64);
        gemm_tn_kernel<<<g_lm, 256, 0, stream>>>(hn, lm_head_w, nullptr,
                                                 out + (size_t)c * CROWS_ * V_, CROWS_, V_, D_);
    }
}

// Round 3
// 12235.741 us; speedup vs baseline: 1.5162x; 1.5162x over previous
//
#include <hip/hip_runtime.h>
#include <math.h>

#define B_ 32
#define L_ 512
#define S_ 37
#define STATIC_ 8
#define D_ 768
#define DI_ 1536
#define N_ 16
#define DTR_ 48
#define NL_ 4
#define V_ 32
#define ROWS_ (B_*L_)      // 16384
#define CB_ 8              // batch chunk
#define CROWS_ (CB_*L_)    // 4096
#define NCH_ (B_/CB_)      // 4
#define NP2_ 1568          // dt_pre(1536) + B(16) + C(16)
#define NP2A_ 1664         // padded to 13*128
#define KE_ 96             // padded embed K (74 -> 96)

typedef __bf16 bf16;
typedef __bf16 bf16x8 __attribute__((ext_vector_type(8)));
typedef float f32x4 __attribute__((ext_vector_type(4)));

typedef __attribute__((address_space(3))) void lds_void;
typedef __attribute__((address_space(1))) const void gmem_void;

__device__ __forceinline__ void gld16(const void* g, void* l) {
    __builtin_amdgcn_global_load_lds((gmem_void*)g, (lds_void*)l, 16, 0, 0);
}

__device__ __forceinline__ float silu_(float x) { return x / (1.f + __expf(-x)); }

// ================= bf16 MFMA GEMM: C[M,Nstore] = A[M,K] @ W[Nalloc,K]^T (+addsrc) =============
// Requires: M%128==0, K%32==0, gridDim.x*128 <= Nalloc (W zero-padded), Nstore = C stride.
template<bool OBF>
__global__ __launch_bounds__(256) void gemm_mfma(
    const bf16* __restrict__ A, const bf16* __restrict__ W,
    const float* __restrict__ addsrc, void* __restrict__ Cv,
    int Nstore, int K)
{
    __shared__ bf16 As[128 * 32];
    __shared__ bf16 Bs[128 * 32];
    const int tid = threadIdx.x;
    const int m0 = blockIdx.y * 128, n0 = blockIdx.x * 128;

    f32x4 acc[4][4];
    #pragma unroll
    for (int i = 0; i < 4; i++)
        #pragma unroll
        for (int j = 0; j < 4; j++)
            acc[i][j] = f32x4{0.f, 0.f, 0.f, 0.f};

    const int srow = tid >> 2, spart = tid & 3;
    const bf16* ag = A + (size_t)(m0 + srow) * K + spart * 8;
    const bf16* wg = W + (size_t)(n0 + srow) * K + spart * 8;
    char* lA = (char*)As + tid * 16;
    char* lB = (char*)Bs + tid * 16;

    const int lane = tid & 63, wv = tid >> 6;
    const int wr = wv >> 1, wc = wv & 1;
    const int colL = lane & 15, quad = lane >> 4;
    const bf16* aRd = As + (wr * 64 + colL) * 32 + quad * 8;
    const bf16* bRd = Bs + (wc * 64 + colL) * 32 + quad * 8;

    for (int kt = 0; kt < K; kt += 32) {
        gld16(ag + kt, lA);
        gld16(ag + kt + (size_t)64 * K, lA + 4096);
        gld16(wg + kt, lB);
        gld16(wg + kt + (size_t)64 * K, lB + 4096);
        __syncthreads();
        bf16x8 fa[4], fb[4];
        #pragma unroll
        for (int i = 0; i < 4; i++) fa[i] = *(const bf16x8*)(aRd + i * 16 * 32);
        #pragma unroll
        for (int j = 0; j < 4; j++) fb[j] = *(const bf16x8*)(bRd + j * 16 * 32);
        #pragma unroll
        for (int i = 0; i < 4; i++)
            #pragma unroll
            for (int j = 0; j < 4; j++)
                acc[i][j] = __builtin_amdgcn_mfma_f32_16x16x32_bf16(fa[i], fb[j], acc[i][j], 0, 0, 0);
        __syncthreads();
    }

    float* Cf = (float*)Cv;
    bf16*  Cb = (bf16*)Cv;
    #pragma unroll
    for (int i = 0; i < 4; i++) {
        #pragma unroll
        for (int j = 0; j < 4; j++) {
            int n = n0 + wc * 64 + j * 16 + colL;
            if (n < Nstore) {
                #pragma unroll
                for (int r = 0; r < 4; r++) {
                    int m = m0 + wr * 64 + i * 16 + quad * 4 + r;
                    float v = acc[i][j][r];
                    if (addsrc) v += addsrc[(size_t)m * Nstore + n];
                    if (OBF) Cb[(size_t)m * Nstore + n] = (bf16)v;
                    else     Cf[(size_t)m * Nstore + n] = v;
                }
            }
        }
    }
}

// ================= small prep kernels =================
__global__ __launch_bounds__(256) void cast_f2b_kernel(const float* __restrict__ s,
                                                       bf16* __restrict__ d) {
    size_t i = (size_t)blockIdx.x * 256 + threadIdx.x;
    d[i] = (bf16)s[i];
}

// lm_head: pad 32x768 -> 128x768 zeros
__global__ __launch_bounds__(256) void pad_lm_kernel(const float* __restrict__ s, bf16* __restrict__ d) {
    int i = blockIdx.x * 256 + threadIdx.x;     // 128*768
    int row = i / D_;
    d[i] = (row < V_) ? (bf16)s[i] : (bf16)0.f;
}

// emb_w: (768 x 74) -> (768 x 96) zero-padded bf16
__global__ __launch_bounds__(256) void pad_embw_kernel(const float* __restrict__ s, bf16* __restrict__ d) {
    int i = blockIdx.x * 256 + threadIdx.x;     // 768*96
    int row = i / KE_, col = i % KE_;
    d[i] = (col < 2 * S_) ? (bf16)s[row * 2 * S_ + col] : (bf16)0.f;
}

// feats: (ROWS x 96) = [x(37) | mask(37) | 0(22)]
__global__ __launch_bounds__(256) void feats_kernel(const float* __restrict__ x,
                                                    const int* __restrict__ mask,
                                                    bf16* __restrict__ d) {
    size_t i = (size_t)blockIdx.x * 256 + threadIdx.x;  // ROWS_*96
    size_t row = i / KE_;
    int col = (int)(i % KE_);
    float v = 0.f;
    if (col < S_) v = x[row * S_ + col];
    else if (col < 2 * S_) v = (float)mask[row * S_ + (col - S_)];
    d[i] = (bf16)v;
}

// Wbig rows 0..1535: Wcomb[d,k] = sum_r dtw[d,r] * xpw[r,k]
__global__ __launch_bounds__(256) void wcomb_kernel(const float* __restrict__ dtw,
                                                    const float* __restrict__ xpw,
                                                    bf16* __restrict__ wbig) {
    int l = blockIdx.y;
    size_t idx = (size_t)blockIdx.x * 256 + threadIdx.x;  // 1536*1536
    int i = (int)(idx / DI_), j = (int)(idx % DI_);
    const float* dr = dtw + ((size_t)l * DI_ + i) * DTR_;
    const float* xr = xpw + (size_t)l * (DTR_ + 2 * N_) * DI_ + j;
    float acc = 0.f;
    #pragma unroll
    for (int r = 0; r < DTR_; r++) acc += dr[r] * xr[(size_t)r * DI_];
    wbig[(size_t)l * NP2A_ * DI_ + idx] = (bf16)acc;
}

// Wbig rows 1536..1663: B/C rows of x_proj_w (rows 48..79), then zero pad
__global__ __launch_bounds__(256) void wbig_bc_kernel(const float* __restrict__ xpw,
                                                      bf16* __restrict__ wbig) {
    int l = blockIdx.y;
    int idx = blockIdx.x * 256 + threadIdx.x;   // 128*1536
    int row = DI_ + idx / DI_, col = idx % DI_;
    float v = 0.f;
    if (row < NP2_) v = xpw[(size_t)l * (DTR_ + 2 * N_) * DI_ + (size_t)(DTR_ + row - DI_) * DI_ + col];
    wbig[(size_t)l * NP2A_ * DI_ + (size_t)row * DI_ + col] = (bf16)v;
}

// sstat[b,d] = emb_b[d] + static_b[d] + dot8(static[b], static_w[d])
__global__ __launch_bounds__(256) void sstat_kernel(const float* __restrict__ stat,
                                                    const float* __restrict__ static_w,
                                                    const float* __restrict__ static_b,
                                                    const float* __restrict__ emb_b,
                                                    float* __restrict__ sstat) {
    int i = blockIdx.x * 256 + threadIdx.x;  // B_*D_
    int d = i % D_, b = i / D_;
    float acc = emb_b[d] + static_b[d];
    const float* sw = static_w + (size_t)d * STATIC_;
    const float* sv = stat + (size_t)b * STATIC_;
    #pragma unroll
    for (int s = 0; s < STATIC_; s++) acc += sv[s] * sw[s];
    sstat[i] = acc;
}

__device__ __forceinline__ void block_reduce2_(float& a, float& b, float* sbuf) {
    #pragma unroll
    for (int off = 32; off > 0; off >>= 1) {
        a += __shfl_down(a, off, 64);
        b += __shfl_down(b, off, 64);
    }
    int lane = threadIdx.x & 63, wid = threadIdx.x >> 6;
    if (lane == 0) { sbuf[wid] = a; sbuf[4 + wid] = b; }
    __syncthreads();
    a = sbuf[0] + sbuf[1] + sbuf[2] + sbuf[3];
    b = sbuf[4] + sbuf[5] + sbuf[6] + sbuf[7];
}

// h = LN(h_pre + sstat[b]) * ln_w + ln_b ; one block per row
__global__ __launch_bounds__(256) void ln_embed_kernel(const float* __restrict__ h_pre,
                                                       const float* __restrict__ sstat,
                                                       const float* __restrict__ ln_w,
                                                       const float* __restrict__ ln_b,
                                                       float* __restrict__ h) {
    int row = blockIdx.x, b = row / L_, tid = threadIdx.x;
    __shared__ float sbuf[8];
    float v[3], sum = 0.f, sq = 0.f;
    #pragma unroll
    for (int j = 0; j < 3; j++) {
        int d = tid + 256 * j;
        v[j] = h_pre[(size_t)row * D_ + d] + sstat[b * D_ + d];
        sum += v[j]; sq += v[j] * v[j];
    }
    block_reduce2_(sum, sq, sbuf);
    float mu = sum * (1.f / D_);
    float rstd = rsqrtf(sq * (1.f / D_) - mu * mu + 1e-5f);
    #pragma unroll
    for (int j = 0; j < 3; j++) {
        int d = tid + 256 * j;
        h[(size_t)row * D_ + d] = (v[j] - mu) * rstd * ln_w[d] + ln_b[d];
    }
}

// rmsnorm fp32 -> bf16, one block per row
__global__ __launch_bounds__(256) void rmsnorm_bf_kernel(const float* __restrict__ h,
                                                         const float* __restrict__ w,
                                                         bf16* __restrict__ out) {
    int row = blockIdx.x, tid = threadIdx.x;
    __shared__ float sbuf[8];
    float v[3], ss = 0.f, dummy = 0.f;
    #pragma unroll
    for (int j = 0; j < 3; j++) {
        v[j] = h[(size_t)row * D_ + tid + 256 * j];
        ss += v[j] * v[j];
    }
    block_reduce2_(ss, dummy, sbuf);
    float rstd = rsqrtf(ss * (1.f / D_) + 1e-5f);
    #pragma unroll
    for (int j = 0; j < 3; j++) {
        int d = tid + 256 * j;
        out[(size_t)row * D_ + d] = (bf16)(v[j] * rstd * w[d]);
    }
}

// causal depthwise conv K=4 + silu : xz_bf (CROWS x 3072, first 1536 cols) -> xc_bf
__global__ __launch_bounds__(256) void conv_silu_kernel(const bf16* __restrict__ xzb,
                                                        const float* __restrict__ cw,
                                                        const float* __restrict__ cb,
                                                        bf16* __restrict__ xcb) {
    size_t idx = (size_t)blockIdx.x * 256 + threadIdx.x;   // CROWS_*DI_
    int d = (int)(idx % DI_);
    size_t row = idx / DI_;
    int t = (int)(row % L_);
    float acc = cb[d];
    const float* w = cw + d * 4;
    if (t >= 3) acc += w[0] * (float)xzb[(row - 3) * (2 * DI_) + d];
    if (t >= 2) acc += w[1] * (float)xzb[(row - 2) * (2 * DI_) + d];
    if (t >= 1) acc += w[2] * (float)xzb[(row - 1) * (2 * DI_) + d];
    acc += w[3] * (float)xzb[row * (2 * DI_) + d];
    xcb[idx] = (bf16)silu_(acc);
}

// fused scan: thread=(b,d,n); softplus, recurrence, shuffle-reduce over n, +D*u, *silu(z)
__global__ __launch_bounds__(256) void scan_fused_kernel(const float* __restrict__ proj2,
                                                         const bf16* __restrict__ xcb,
                                                         const bf16* __restrict__ xzb,
                                                         const float* __restrict__ A_log,
                                                         const float* __restrict__ dt_bias,
                                                         const float* __restrict__ Dp,
                                                         bf16* __restrict__ yb) {
    int tid = threadIdx.x;
    int n = tid & 15;
    int d = blockIdx.x * 16 + (tid >> 4);
    int b = blockIdx.y;
    float Av = -__expf(A_log[(size_t)d * N_ + n]);
    float bias = dt_bias[d];
    float Dv = Dp[d];
    float h = 0.f;
    for (int t = 0; t < L_; t++) {
        size_t row = (size_t)b * L_ + t;
        const float* pr = proj2 + row * NP2_;
        float dpre = pr[d] + bias;
        float dtv = fmaxf(dpre, 0.f) + log1pf(__expf(-fabsf(dpre)));
        float u = (float)xcb[row * DI_ + d];
        float Bn = pr[DI_ + n];
        float Cn = pr[DI_ + N_ + n];
        float dA = __expf(dtv * Av);
        h = dA * h + dtv * u * Bn;
        float p = h * Cn;
        p += __shfl_xor(p, 1);
        p += __shfl_xor(p, 2);
        p += __shfl_xor(p, 4);
        p += __shfl_xor(p, 8);
        if (n == 0) {
            float z = (float)xzb[row * (2 * DI_) + DI_ + d];
            yb[row * DI_ + d] = (bf16)((p + Dv * u) * silu_(z));
        }
    }
}

extern "C" void kernel_launch(void* const* d_in, const int* in_sizes, int n_in,
                              void* d_out, int out_size, void* d_ws, size_t ws_size,
                              hipStream_t stream) {
    const float* x        = (const float*)d_in[0];
    const float* stat     = (const float*)d_in[1];
    const int*   mask     = (const int*)d_in[3];
    const float* emb_w    = (const float*)d_in[5];
    const float* emb_b    = (const float*)d_in[6];
    const float* static_w = (const float*)d_in[7];
    const float* static_b = (const float*)d_in[8];
    const float* ln_w     = (const float*)d_in[9];
    const float* ln_b     = (const float*)d_in[10];
    const float* norm_w   = (const float*)d_in[11];
    const float* in_proj_w  = (const float*)d_in[12];
    const float* conv_w   = (const float*)d_in[13];
    const float* conv_b   = (const float*)d_in[14];
    const float* x_proj_w = (const float*)d_in[15];
    const float* dt_proj_w= (const float*)d_in[16];
    const float* dt_proj_b= (const float*)d_in[17];
    const float* A_log    = (const float*)d_in[18];
    const float* D_param  = (const float*)d_in[19];
    const float* out_proj_w = (const float*)d_in[20];
    const float* norm_f_w = (const float*)d_in[21];
    const float* lm_head_w= (const float*)d_in[22];
    float* out = (float*)d_out;

    // ---- workspace layout (bytes), total ~185 MB ----
    char* p = (char*)d_ws;
    float* h      = (float*)p;            p += (size_t)ROWS_ * D_ * 4;          // 50.3 MB
    bf16*  hn_bf  = (bf16*)p;             p += (size_t)CROWS_ * D_ * 2;         // 6.3
    char*  xz_region = p;                                                      // h_pre alias start
    bf16*  xz_bf  = (bf16*)p;             p += (size_t)CROWS_ * 2 * DI_ * 2;    // 25.2
    bf16*  xc_bf  = (bf16*)p;             p += (size_t)CROWS_ * DI_ * 2;        // 12.6
    float* proj2  = (float*)p;            p += (size_t)CROWS_ * NP2_ * 4;       // 25.7
    bf16*  y_bf   = (bf16*)p;             p += (size_t)CROWS_ * DI_ * 2;        // 12.6
    bf16*  inw_bf = (bf16*)p;             p += (size_t)NL_ * 2 * DI_ * D_ * 2;  // 18.9
    bf16*  outw_bf= (bf16*)p;             p += (size_t)NL_ * D_ * DI_ * 2;      // 9.4
    bf16*  wbig   = (bf16*)p;             p += (size_t)NL_ * NP2A_ * DI_ * 2;   // 20.4
    bf16*  lmw_bf = (bf16*)p;             p += (size_t)128 * D_ * 2;
    bf16*  embw_bf= (bf16*)p;             p += (size_t)D_ * KE_ * 2;
    bf16*  feats  = (bf16*)p;             p += (size_t)ROWS_ * KE_ * 2;         // 3.1
    float* sstat  = (float*)p;            p += (size_t)B_ * D_ * 4;
    float* h_pre  = (float*)xz_region;    // 50.3 MB alias over xz/xc/proj2 (dead then)

    // ---- weight prep (every launch; no persistent state allowed) ----
    cast_f2b_kernel<<<(NL_ * 2 * DI_ * D_) / 256, 256, 0, stream>>>(in_proj_w, inw_bf);
    cast_f2b_kernel<<<(NL_ * D_ * DI_) / 256, 256, 0, stream>>>(out_proj_w, outw_bf);
    pad_lm_kernel<<<(128 * D_) / 256, 256, 0, stream>>>(lm_head_w, lmw_bf);
    pad_embw_kernel<<<(D_ * KE_) / 256, 256, 0, stream>>>(emb_w, embw_bf);
    feats_kernel<<<(ROWS_ * KE_) / 256, 256, 0, stream>>>(x, mask, feats);
    dim3 gwc((DI_ * DI_) / 256, NL_);
    wcomb_kernel<<<gwc, 256, 0, stream>>>(dt_proj_w, x_proj_w, wbig);
    dim3 gbc((128 * DI_) / 256, NL_);
    wbig_bc_kernel<<<gbc, 256, 0, stream>>>(x_proj_w, wbig);
    sstat_kernel<<<(B_ * D_) / 256, 256, 0, stream>>>(stat, static_w, static_b, emb_b, sstat);

    // ---- embed: h_pre = feats @ embw^T  (MFMA), then LN ----
    dim3 ge(D_ / 128, ROWS_ / 128);
    gemm_mfma<false><<<ge, 256, 0, stream>>>(feats, embw_bf, nullptr, h_pre, D_, KE_);
    ln_embed_kernel<<<ROWS_, 256, 0, stream>>>(h_pre, sstat, ln_w, ln_b, h);

    // ---- layers ----
    for (int l = 0; l < NL_; l++) {
        for (int c = 0; c < NCH_; c++) {
            float* hc = h + (size_t)c * CROWS_ * D_;

            rmsnorm_bf_kernel<<<CROWS_, 256, 0, stream>>>(hc, norm_w + (size_t)l * D_, hn_bf);

            dim3 g1((2 * DI_) / 128, CROWS_ / 128);
            gemm_mfma<true><<<g1, 256, 0, stream>>>(hn_bf, inw_bf + (size_t)l * 2 * DI_ * D_,
                                                    nullptr, xz_bf, 2 * DI_, D_);

            conv_silu_kernel<<<(CROWS_ * DI_) / 256, 256, 0, stream>>>(
                xz_bf, conv_w + (size_t)l * DI_ * 4, conv_b + (size_t)l * DI_, xc_bf);

            dim3 g2(NP2A_ / 128, CROWS_ / 128);
            gemm_mfma<false><<<g2, 256, 0, stream>>>(xc_bf, wbig + (size_t)l * NP2A_ * DI_,
                                                     nullptr, proj2, NP2_, DI_);

            dim3 gs(DI_ / 16, CB_);
            scan_fused_kernel<<<gs, 256, 0, stream>>>(proj2, xc_bf, xz_bf,
                                                      A_log + (size_t)l * DI_ * N_,
                                                      dt_proj_b + (size_t)l * DI_,
                                                      D_param + (size_t)l * DI_, y_bf);

            dim3 g3(D_ / 128, CROWS_ / 128);
            gemm_mfma<false><<<g3, 256, 0, stream>>>(y_bf, outw_bf + (size_t)l * D_ * DI_,
                                                     hc, hc, D_, DI_);
        }
    }

    // ---- final rmsnorm + lm_head per chunk ----
    for (int c = 0; c < NCH_; c++) {
        float* hc = h + (size_t)c * CROWS_ * D_;
        rmsnorm_bf_kernel<<<CROWS_, 256, 0, stream>>>(hc, norm_f_w, hn_bf);
        dim3 glm(1, CROWS_ / 128);
        gemm_mfma<false><<<glm, 256, 0, stream>>>(hn_bf, lmw_bf, nullptr,
                                                  out + (size_t)c * CROWS_ * V_, V_, D_);
    }
}

// Round 4
// 8872.012 us; speedup vs baseline: 2.0910x; 1.3791x over previous
//
#include <hip/hip_runtime.h>
#include <math.h>

#define B_ 32
#define L_ 512
#define S_ 37
#define STATIC_ 8
#define D_ 768
#define DI_ 1536
#define N_ 16
#define DTR_ 48
#define NL_ 4
#define V_ 32
#define ROWS_ (B_*L_)      // 16384
#define CB_ 8              // batch chunk
#define CROWS_ (CB_*L_)    // 4096
#define NCH_ (B_/CB_)      // 4
#define NP2_ 1568          // dt_pre(1536) + B(16) + C(16)
#define NP2A_ 1664         // padded to 13*128
#define KE_ 96             // padded embed K (74 -> 96)

typedef __bf16 bf16;
typedef __bf16 bf16x8 __attribute__((ext_vector_type(8)));
typedef __bf16 bf16x2 __attribute__((ext_vector_type(2)));
typedef float f32x4 __attribute__((ext_vector_type(4)));

typedef __attribute__((address_space(3))) void lds_void;
typedef __attribute__((address_space(1))) const void gmem_void;

__device__ __forceinline__ void gld16(const void* g, void* l) {
    __builtin_amdgcn_global_load_lds((gmem_void*)g, (lds_void*)l, 16, 0, 0);
}

__device__ __forceinline__ float silu_(float x) { return x / (1.f + __expf(-x)); }
__device__ __forceinline__ float softplus_(float x) {
    return fmaxf(x, 0.f) + __logf(1.f + __expf(-fabsf(x)));
}

// ================= bf16 MFMA GEMM: C[M,*] = A[M,K] @ W[Nalloc,K]^T =================
// MODE 0: f32 out (+addsrc) stride Nstore; MODE 1: bf16 out stride Nstore;
// MODE 2: scan-prep: n<DI_ -> duv pack (softplus, du=dtv*u with u=A[m,n]); DI_<=n<NP2_ -> bc[m*32+n-DI_]
template<int MODE>
__global__ __launch_bounds__(256) void gemm_mfma(
    const bf16* __restrict__ A, const bf16* __restrict__ W,
    const float* __restrict__ addsrc, void* __restrict__ Cv,
    int Nstore, int K,
    const float* __restrict__ dt_bias, bf16x2* __restrict__ duv,
    float* __restrict__ bc)
{
    __shared__ bf16 As[128 * 32];
    __shared__ bf16 Bs[128 * 32];
    const int tid = threadIdx.x;
    const int m0 = blockIdx.y * 128, n0 = blockIdx.x * 128;

    f32x4 acc[4][4];
    #pragma unroll
    for (int i = 0; i < 4; i++)
        #pragma unroll
        for (int j = 0; j < 4; j++)
            acc[i][j] = f32x4{0.f, 0.f, 0.f, 0.f};

    const int srow = tid >> 2, spart = tid & 3;
    const bf16* ag = A + (size_t)(m0 + srow) * K + spart * 8;
    const bf16* wg = W + (size_t)(n0 + srow) * K + spart * 8;
    char* lA = (char*)As + tid * 16;
    char* lB = (char*)Bs + tid * 16;

    const int lane = tid & 63, wv = tid >> 6;
    const int wr = wv >> 1, wc = wv & 1;
    const int colL = lane & 15, quad = lane >> 4;
    const bf16* aRd = As + (wr * 64 + colL) * 32 + quad * 8;
    const bf16* bRd = Bs + (wc * 64 + colL) * 32 + quad * 8;

    for (int kt = 0; kt < K; kt += 32) {
        gld16(ag + kt, lA);
        gld16(ag + kt + (size_t)64 * K, lA + 4096);
        gld16(wg + kt, lB);
        gld16(wg + kt + (size_t)64 * K, lB + 4096);
        __syncthreads();
        bf16x8 fa[4], fb[4];
        #pragma unroll
        for (int i = 0; i < 4; i++) fa[i] = *(const bf16x8*)(aRd + i * 16 * 32);
        #pragma unroll
        for (int j = 0; j < 4; j++) fb[j] = *(const bf16x8*)(bRd + j * 16 * 32);
        #pragma unroll
        for (int i = 0; i < 4; i++)
            #pragma unroll
            for (int j = 0; j < 4; j++)
                acc[i][j] = __builtin_amdgcn_mfma_f32_16x16x32_bf16(fa[i], fb[j], acc[i][j], 0, 0, 0);
        __syncthreads();
    }

    float* Cf = (float*)Cv;
    bf16*  Cb = (bf16*)Cv;
    #pragma unroll
    for (int i = 0; i < 4; i++) {
        #pragma unroll
        for (int j = 0; j < 4; j++) {
            int n = n0 + wc * 64 + j * 16 + colL;
            #pragma unroll
            for (int r = 0; r < 4; r++) {
                int m = m0 + wr * 64 + i * 16 + quad * 4 + r;
                float v = acc[i][j][r];
                if (MODE == 2) {
                    if (n < DI_) {
                        float dtv = softplus_(v + dt_bias[n]);
                        float u = (float)A[(size_t)m * DI_ + n];
                        duv[(size_t)m * DI_ + n] = bf16x2{(bf16)(dtv * u), (bf16)dtv};
                    } else if (n < NP2_) {
                        bc[(size_t)m * 32 + (n - DI_)] = v;
                    }
                } else if (n < Nstore) {
                    if (addsrc) v += addsrc[(size_t)m * Nstore + n];
                    if (MODE == 1) Cb[(size_t)m * Nstore + n] = (bf16)v;
                    else           Cf[(size_t)m * Nstore + n] = v;
                }
            }
        }
    }
}

// ================= small prep kernels =================
__global__ __launch_bounds__(256) void cast_f2b_kernel(const float* __restrict__ s,
                                                       bf16* __restrict__ d) {
    size_t i = (size_t)blockIdx.x * 256 + threadIdx.x;
    d[i] = (bf16)s[i];
}

__global__ __launch_bounds__(256) void pad_lm_kernel(const float* __restrict__ s, bf16* __restrict__ d) {
    int i = blockIdx.x * 256 + threadIdx.x;     // 128*768
    int row = i / D_;
    d[i] = (row < V_) ? (bf16)s[i] : (bf16)0.f;
}

__global__ __launch_bounds__(256) void pad_embw_kernel(const float* __restrict__ s, bf16* __restrict__ d) {
    int i = blockIdx.x * 256 + threadIdx.x;     // 768*96
    int row = i / KE_, col = i % KE_;
    d[i] = (col < 2 * S_) ? (bf16)s[row * 2 * S_ + col] : (bf16)0.f;
}

__global__ __launch_bounds__(256) void feats_kernel(const float* __restrict__ x,
                                                    const int* __restrict__ mask,
                                                    bf16* __restrict__ d) {
    size_t i = (size_t)blockIdx.x * 256 + threadIdx.x;  // ROWS_*96
    size_t row = i / KE_;
    int col = (int)(i % KE_);
    float v = 0.f;
    if (col < S_) v = x[row * S_ + col];
    else if (col < 2 * S_) v = (float)mask[row * S_ + (col - S_)];
    d[i] = (bf16)v;
}

// Wbig rows 0..1535: Wcomb[d,k] = sum_r dtw[d,r] * xpw[r,k]
__global__ __launch_bounds__(256) void wcomb_kernel(const float* __restrict__ dtw,
                                                    const float* __restrict__ xpw,
                                                    bf16* __restrict__ wbig) {
    int l = blockIdx.y;
    size_t idx = (size_t)blockIdx.x * 256 + threadIdx.x;  // 1536*1536
    int i = (int)(idx / DI_), j = (int)(idx % DI_);
    const float* dr = dtw + ((size_t)l * DI_ + i) * DTR_;
    const float* xr = xpw + (size_t)l * (DTR_ + 2 * N_) * DI_ + j;
    float acc = 0.f;
    #pragma unroll
    for (int r = 0; r < DTR_; r++) acc += dr[r] * xr[(size_t)r * DI_];
    wbig[(size_t)l * NP2A_ * DI_ + idx] = (bf16)acc;
}

// Wbig rows 1536..1663: B/C rows of x_proj_w (rows 48..79), then zero pad
__global__ __launch_bounds__(256) void wbig_bc_kernel(const float* __restrict__ xpw,
                                                      bf16* __restrict__ wbig) {
    int l = blockIdx.y;
    int idx = blockIdx.x * 256 + threadIdx.x;   // 128*1536
    int row = DI_ + idx / DI_, col = idx % DI_;
    float v = 0.f;
    if (row < NP2_) v = xpw[(size_t)l * (DTR_ + 2 * N_) * DI_ + (size_t)(DTR_ + row - DI_) * DI_ + col];
    wbig[(size_t)l * NP2A_ * DI_ + (size_t)row * DI_ + col] = (bf16)v;
}

__global__ __launch_bounds__(256) void sstat_kernel(const float* __restrict__ stat,
                                                    const float* __restrict__ static_w,
                                                    const float* __restrict__ static_b,
                                                    const float* __restrict__ emb_b,
                                                    float* __restrict__ sstat) {
    int i = blockIdx.x * 256 + threadIdx.x;  // B_*D_
    int d = i % D_, b = i / D_;
    float acc = emb_b[d] + static_b[d];
    const float* sw = static_w + (size_t)d * STATIC_;
    const float* sv = stat + (size_t)b * STATIC_;
    #pragma unroll
    for (int s = 0; s < STATIC_; s++) acc += sv[s] * sw[s];
    sstat[i] = acc;
}

__device__ __forceinline__ void block_reduce2_(float& a, float& b, float* sbuf) {
    #pragma unroll
    for (int off = 32; off > 0; off >>= 1) {
        a += __shfl_down(a, off, 64);
        b += __shfl_down(b, off, 64);
    }
    int lane = threadIdx.x & 63, wid = threadIdx.x >> 6;
    if (lane == 0) { sbuf[wid] = a; sbuf[4 + wid] = b; }
    __syncthreads();
    a = sbuf[0] + sbuf[1] + sbuf[2] + sbuf[3];
    b = sbuf[4] + sbuf[5] + sbuf[6] + sbuf[7];
}

__global__ __launch_bounds__(256) void ln_embed_kernel(const float* __restrict__ h_pre,
                                                       const float* __restrict__ sstat,
                                                       const float* __restrict__ ln_w,
                                                       const float* __restrict__ ln_b,
                                                       float* __restrict__ h) {
    int row = blockIdx.x, b = row / L_, tid = threadIdx.x;
    __shared__ float sbuf[8];
    float v[3], sum = 0.f, sq = 0.f;
    #pragma unroll
    for (int j = 0; j < 3; j++) {
        int d = tid + 256 * j;
        v[j] = h_pre[(size_t)row * D_ + d] + sstat[b * D_ + d];
        sum += v[j]; sq += v[j] * v[j];
    }
    block_reduce2_(sum, sq, sbuf);
    float mu = sum * (1.f / D_);
    float rstd = rsqrtf(sq * (1.f / D_) - mu * mu + 1e-5f);
    #pragma unroll
    for (int j = 0; j < 3; j++) {
        int d = tid + 256 * j;
        h[(size_t)row * D_ + d] = (v[j] - mu) * rstd * ln_w[d] + ln_b[d];
    }
}

__global__ __launch_bounds__(256) void rmsnorm_bf_kernel(const float* __restrict__ h,
                                                         const float* __restrict__ w,
                                                         bf16* __restrict__ out) {
    int row = blockIdx.x, tid = threadIdx.x;
    __shared__ float sbuf[8];
    float v[3], ss = 0.f, dummy = 0.f;
    #pragma unroll
    for (int j = 0; j < 3; j++) {
        v[j] = h[(size_t)row * D_ + tid + 256 * j];
        ss += v[j] * v[j];
    }
    block_reduce2_(ss, dummy, sbuf);
    float rstd = rsqrtf(ss * (1.f / D_) + 1e-5f);
    #pragma unroll
    for (int j = 0; j < 3; j++) {
        int d = tid + 256 * j;
        out[(size_t)row * D_ + d] = (bf16)(v[j] * rstd * w[d]);
    }
}

// conv K=4 + silu -> xc ; also gate pack: off = D*u*silu(z), gz = silu(z)
__global__ __launch_bounds__(256) void conv_silu_kernel(const bf16* __restrict__ xzb,
                                                        const float* __restrict__ cw,
                                                        const float* __restrict__ cb,
                                                        const float* __restrict__ Dp,
                                                        bf16* __restrict__ xcb,
                                                        bf16x2* __restrict__ offgz) {
    size_t idx = (size_t)blockIdx.x * 256 + threadIdx.x;   // CROWS_*DI_
    int d = (int)(idx % DI_);
    size_t row = idx / DI_;
    int t = (int)(row % L_);
    float acc = cb[d];
    const float* w = cw + d * 4;
    if (t >= 3) acc += w[0] * (float)xzb[(row - 3) * (2 * DI_) + d];
    if (t >= 2) acc += w[1] * (float)xzb[(row - 2) * (2 * DI_) + d];
    if (t >= 1) acc += w[2] * (float)xzb[(row - 1) * (2 * DI_) + d];
    acc += w[3] * (float)xzb[row * (2 * DI_) + d];
    float u = silu_(acc);
    xcb[idx] = (bf16)u;
    float z = (float)xzb[row * (2 * DI_) + DI_ + d];
    float gz = silu_(z);
    offgz[idx] = bf16x2{(bf16)(Dp[d] * u * gz), (bf16)gz};
}

// lean scan: per t: 1 exp + 3 fma/mul + 4 shfl-adds; all per-(row,d) work precomputed
__global__ __launch_bounds__(256) void scan2_kernel(const float* __restrict__ bc,
                                                    const bf16x2* __restrict__ duv,
                                                    const bf16x2* __restrict__ offgz,
                                                    const float* __restrict__ A_log,
                                                    bf16* __restrict__ yb) {
    int tid = threadIdx.x;
    int n = tid & 15;
    int d = blockIdx.x * 16 + (tid >> 4);
    int b = blockIdx.y;
    float Av = -__expf(A_log[(size_t)d * N_ + n]);
    float h = 0.f;
    size_t rbase = (size_t)b * L_;
    const float*  pBC  = bc    + rbase * 32;
    const bf16x2* pduv = duv   + rbase * DI_ + d;
    const bf16x2* pog  = offgz + rbase * DI_ + d;
    bf16*         py   = yb    + rbase * DI_ + d;
    #pragma unroll 2
    for (int t = 0; t < L_; t++) {
        bf16x2 dv = *pduv;
        float du = (float)dv.x, dtv = (float)dv.y;
        float Bn = pBC[n], Cn = pBC[16 + n];
        float dA = __expf(dtv * Av);
        h = dA * h + du * Bn;
        float p = h * Cn;
        p += __shfl_xor(p, 1);
        p += __shfl_xor(p, 2);
        p += __shfl_xor(p, 4);
        p += __shfl_xor(p, 8);
        if (n == 0) {
            bf16x2 og = *pog;
            *py = (bf16)(p * (float)og.y + (float)og.x);
        }
        pBC += 32; pduv += DI_; pog += DI_; py += DI_;
    }
}

extern "C" void kernel_launch(void* const* d_in, const int* in_sizes, int n_in,
                              void* d_out, int out_size, void* d_ws, size_t ws_size,
                              hipStream_t stream) {
    const float* x        = (const float*)d_in[0];
    const float* stat     = (const float*)d_in[1];
    const int*   mask     = (const int*)d_in[3];
    const float* emb_w    = (const float*)d_in[5];
    const float* emb_b    = (const float*)d_in[6];
    const float* static_w = (const float*)d_in[7];
    const float* static_b = (const float*)d_in[8];
    const float* ln_w     = (const float*)d_in[9];
    const float* ln_b     = (const float*)d_in[10];
    const float* norm_w   = (const float*)d_in[11];
    const float* in_proj_w  = (const float*)d_in[12];
    const float* conv_w   = (const float*)d_in[13];
    const float* conv_b   = (const float*)d_in[14];
    const float* x_proj_w = (const float*)d_in[15];
    const float* dt_proj_w= (const float*)d_in[16];
    const float* dt_proj_b= (const float*)d_in[17];
    const float* A_log    = (const float*)d_in[18];
    const float* D_param  = (const float*)d_in[19];
    const float* out_proj_w = (const float*)d_in[20];
    const float* norm_f_w = (const float*)d_in[21];
    const float* lm_head_w= (const float*)d_in[22];
    float* out = (float*)d_out;

    // ---- workspace layout (bytes), total ~211 MB ----
    char* p = (char*)d_ws;
    float*  h      = (float*)p;           p += (size_t)ROWS_ * D_ * 4;          // 50.3 MB
    bf16*   hn_bf  = (bf16*)p;            p += (size_t)CROWS_ * D_ * 2;         // 6.3
    char*   xz_region = p;                                                      // h_pre alias start
    bf16*   xz_bf  = (bf16*)p;            p += (size_t)CROWS_ * 2 * DI_ * 2;    // 25.2
    bf16*   xc_bf  = (bf16*)p;            p += (size_t)CROWS_ * DI_ * 2;        // 12.6
    bf16x2* duv    = (bf16x2*)p;          p += (size_t)CROWS_ * DI_ * 4;        // 25.2
    bf16x2* offgz  = (bf16x2*)p;          p += (size_t)CROWS_ * DI_ * 4;        // 25.2
    float*  bc     = (float*)p;           p += (size_t)CROWS_ * 32 * 4;         // 0.5
    bf16*   y_bf   = (bf16*)p;            p += (size_t)CROWS_ * DI_ * 2;        // 12.6
    bf16*   inw_bf = (bf16*)p;            p += (size_t)NL_ * 2 * DI_ * D_ * 2;  // 18.9
    bf16*   outw_bf= (bf16*)p;            p += (size_t)NL_ * D_ * DI_ * 2;      // 9.4
    bf16*   wbig   = (bf16*)p;            p += (size_t)NL_ * NP2A_ * DI_ * 2;   // 20.4
    bf16*   lmw_bf = (bf16*)p;            p += (size_t)128 * D_ * 2;
    bf16*   embw_bf= (bf16*)p;            p += (size_t)D_ * KE_ * 2;
    bf16*   feats  = (bf16*)p;            p += (size_t)ROWS_ * KE_ * 2;         // 3.1
    float*  sstat  = (float*)p;           p += (size_t)B_ * D_ * 4;
    float*  h_pre  = (float*)xz_region;   // 50.3 MB alias over xz/xc/duv (dead then)

    // ---- weight prep ----
    cast_f2b_kernel<<<(NL_ * 2 * DI_ * D_) / 256, 256, 0, stream>>>(in_proj_w, inw_bf);
    cast_f2b_kernel<<<(NL_ * D_ * DI_) / 256, 256, 0, stream>>>(out_proj_w, outw_bf);
    pad_lm_kernel<<<(128 * D_) / 256, 256, 0, stream>>>(lm_head_w, lmw_bf);
    pad_embw_kernel<<<(D_ * KE_) / 256, 256, 0, stream>>>(emb_w, embw_bf);
    feats_kernel<<<(ROWS_ * KE_) / 256, 256, 0, stream>>>(x, mask, feats);
    dim3 gwc((DI_ * DI_) / 256, NL_);
    wcomb_kernel<<<gwc, 256, 0, stream>>>(dt_proj_w, x_proj_w, wbig);
    dim3 gbc((128 * DI_) / 256, NL_);
    wbig_bc_kernel<<<gbc, 256, 0, stream>>>(x_proj_w, wbig);
    sstat_kernel<<<(B_ * D_) / 256, 256, 0, stream>>>(stat, static_w, static_b, emb_b, sstat);

    // ---- embed + LN ----
    dim3 ge(D_ / 128, ROWS_ / 128);
    gemm_mfma<0><<<ge, 256, 0, stream>>>(feats, embw_bf, nullptr, h_pre, D_, KE_,
                                         nullptr, nullptr, nullptr);
    ln_embed_kernel<<<ROWS_, 256, 0, stream>>>(h_pre, sstat, ln_w, ln_b, h);

    // ---- layers ----
    for (int l = 0; l < NL_; l++) {
        for (int c = 0; c < NCH_; c++) {
            float* hc = h + (size_t)c * CROWS_ * D_;

            rmsnorm_bf_kernel<<<CROWS_, 256, 0, stream>>>(hc, norm_w + (size_t)l * D_, hn_bf);

            dim3 g1((2 * DI_) / 128, CROWS_ / 128);
            gemm_mfma<1><<<g1, 256, 0, stream>>>(hn_bf, inw_bf + (size_t)l * 2 * DI_ * D_,
                                                 nullptr, xz_bf, 2 * DI_, D_,
                                                 nullptr, nullptr, nullptr);

            conv_silu_kernel<<<(CROWS_ * DI_) / 256, 256, 0, stream>>>(
                xz_bf, conv_w + (size_t)l * DI_ * 4, conv_b + (size_t)l * DI_,
                D_param + (size_t)l * DI_, xc_bf, offgz);

            dim3 g2(NP2A_ / 128, CROWS_ / 128);
            gemm_mfma<2><<<g2, 256, 0, stream>>>(xc_bf, wbig + (size_t)l * NP2A_ * DI_,
                                                 nullptr, nullptr, NP2_, DI_,
                                                 dt_proj_b + (size_t)l * DI_, duv, bc);

            dim3 gs(DI_ / 16, CB_);
            scan2_kernel<<<gs, 256, 0, stream>>>(bc, duv, offgz,
                                                 A_log + (size_t)l * DI_ * N_, y_bf);

            dim3 g3(D_ / 128, CROWS_ / 128);
            gemm_mfma<0><<<g3, 256, 0, stream>>>(y_bf, outw_bf + (size_t)l * D_ * DI_,
                                                 hc, hc, D_, DI_,
                                                 nullptr, nullptr, nullptr);
        }
    }

    // ---- final rmsnorm + lm_head ----
    for (int c = 0; c < NCH_; c++) {
        float* hc = h + (size_t)c * CROWS_ * D_;
        rmsnorm_bf_kernel<<<CROWS_, 256, 0, stream>>>(hc, norm_f_w, hn_bf);
        dim3 glm(1, CROWS_ / 128);
        gemm_mfma<0><<<glm, 256, 0, stream>>>(hn_bf, lmw_bf, nullptr,
                                              out + (size_t)c * CROWS_ * V_, V_, D_,
                                              nullptr, nullptr, nullptr);
    }
}

// Round 5
// 5502.628 us; speedup vs baseline: 3.3714x; 1.6123x over previous
//
#include <hip/hip_runtime.h>
#include <math.h>

#define B_ 32
#define L_ 512
#define S_ 37
#define STATIC_ 8
#define D_ 768
#define DI_ 1536
#define N_ 16
#define DTR_ 48
#define NL_ 4
#define V_ 32
#define ROWS_ (B_*L_)      // 16384
#define CB_ 8              // batch chunk
#define CROWS_ (CB_*L_)    // 4096
#define NCH_ (B_/CB_)      // 4
#define NP2_ 1568          // dt_pre(1536) + B(16) + C(16)
#define NP2A_ 1664         // padded to 13*128
#define KE_ 96             // padded embed K (74 -> 96)
#define UU_ 16             // scan software-pipeline depth

typedef __bf16 bf16;
typedef __bf16 bf16x8 __attribute__((ext_vector_type(8)));
typedef __bf16 bf16x2 __attribute__((ext_vector_type(2)));
typedef float f32x4 __attribute__((ext_vector_type(4)));

typedef __attribute__((address_space(3))) void lds_void;
typedef __attribute__((address_space(1))) const void gmem_void;

__device__ __forceinline__ void gld16(const void* g, void* l) {
    __builtin_amdgcn_global_load_lds((gmem_void*)g, (lds_void*)l, 16, 0, 0);
}

__device__ __forceinline__ float silu_(float x) { return x / (1.f + __expf(-x)); }
__device__ __forceinline__ float softplus_(float x) {
    return fmaxf(x, 0.f) + __logf(1.f + __expf(-fabsf(x)));
}
__device__ __forceinline__ unsigned pack_bf2_(float a, float b) {
    bf16x2 v{(bf16)a, (bf16)b};
    return __builtin_bit_cast(unsigned, v);
}

// ================= bf16 MFMA GEMM: C[M,*] = A[M,K] @ W[Nalloc,K]^T =================
// MODE 0: f32 out (+addsrc); MODE 1: bf16 out;
// MODE 2: scan-prep: n<DI_ -> scanin[m*DI_+n].x = pack(du,dtv); DI_<=n<NP2_ -> interleaved bc
template<int MODE>
__global__ __launch_bounds__(256) void gemm_mfma(
    const bf16* __restrict__ A, const bf16* __restrict__ W,
    const float* __restrict__ addsrc, void* __restrict__ Cv,
    int Nstore, int K,
    const float* __restrict__ dt_bias, unsigned* __restrict__ scanw,
    float* __restrict__ bc)
{
    __shared__ bf16 As[128 * 32];
    __shared__ bf16 Bs[128 * 32];
    const int tid = threadIdx.x;
    const int m0 = blockIdx.y * 128, n0 = blockIdx.x * 128;

    f32x4 acc[4][4];
    #pragma unroll
    for (int i = 0; i < 4; i++)
        #pragma unroll
        for (int j = 0; j < 4; j++)
            acc[i][j] = f32x4{0.f, 0.f, 0.f, 0.f};

    const int srow = tid >> 2, spart = tid & 3;
    const bf16* ag = A + (size_t)(m0 + srow) * K + spart * 8;
    const bf16* wg = W + (size_t)(n0 + srow) * K + spart * 8;
    char* lA = (char*)As + tid * 16;
    char* lB = (char*)Bs + tid * 16;

    const int lane = tid & 63, wv = tid >> 6;
    const int wr = wv >> 1, wc = wv & 1;
    const int colL = lane & 15, quad = lane >> 4;
    const bf16* aRd = As + (wr * 64 + colL) * 32 + quad * 8;
    const bf16* bRd = Bs + (wc * 64 + colL) * 32 + quad * 8;

    for (int kt = 0; kt < K; kt += 32) {
        gld16(ag + kt, lA);
        gld16(ag + kt + (size_t)64 * K, lA + 4096);
        gld16(wg + kt, lB);
        gld16(wg + kt + (size_t)64 * K, lB + 4096);
        __syncthreads();
        bf16x8 fa[4], fb[4];
        #pragma unroll
        for (int i = 0; i < 4; i++) fa[i] = *(const bf16x8*)(aRd + i * 16 * 32);
        #pragma unroll
        for (int j = 0; j < 4; j++) fb[j] = *(const bf16x8*)(bRd + j * 16 * 32);
        #pragma unroll
        for (int i = 0; i < 4; i++)
            #pragma unroll
            for (int j = 0; j < 4; j++)
                acc[i][j] = __builtin_amdgcn_mfma_f32_16x16x32_bf16(fa[i], fb[j], acc[i][j], 0, 0, 0);
        __syncthreads();
    }

    float* Cf = (float*)Cv;
    bf16*  Cb = (bf16*)Cv;
    #pragma unroll
    for (int i = 0; i < 4; i++) {
        #pragma unroll
        for (int j = 0; j < 4; j++) {
            int n = n0 + wc * 64 + j * 16 + colL;
            #pragma unroll
            for (int r = 0; r < 4; r++) {
                int m = m0 + wr * 64 + i * 16 + quad * 4 + r;
                float v = acc[i][j][r];
                if (MODE == 2) {
                    if (n < DI_) {
                        float dtv = softplus_(v + dt_bias[n]);
                        float u = (float)A[(size_t)m * DI_ + n];
                        scanw[2 * ((size_t)m * DI_ + n)] = pack_bf2_(dtv * u, dtv);
                    } else if (n < NP2_) {
                        int jj = n - DI_;
                        int pos = (jj < 16) ? (2 * jj) : (2 * (jj - 16) + 1);
                        bc[(size_t)m * 32 + pos] = v;
                    }
                } else if (n < Nstore) {
                    if (addsrc) v += addsrc[(size_t)m * Nstore + n];
                    if (MODE == 1) Cb[(size_t)m * Nstore + n] = (bf16)v;
                    else           Cf[(size_t)m * Nstore + n] = v;
                }
            }
        }
    }
}

// ================= small prep kernels =================
__global__ __launch_bounds__(256) void cast_f2b_kernel(const float* __restrict__ s,
                                                       bf16* __restrict__ d) {
    size_t i = (size_t)blockIdx.x * 256 + threadIdx.x;
    d[i] = (bf16)s[i];
}

__global__ __launch_bounds__(256) void pad_lm_kernel(const float* __restrict__ s, bf16* __restrict__ d) {
    int i = blockIdx.x * 256 + threadIdx.x;     // 128*768
    int row = i / D_;
    d[i] = (row < V_) ? (bf16)s[i] : (bf16)0.f;
}

__global__ __launch_bounds__(256) void pad_embw_kernel(const float* __restrict__ s, bf16* __restrict__ d) {
    int i = blockIdx.x * 256 + threadIdx.x;     // 768*96
    int row = i / KE_, col = i % KE_;
    d[i] = (col < 2 * S_) ? (bf16)s[row * 2 * S_ + col] : (bf16)0.f;
}

__global__ __launch_bounds__(256) void feats_kernel(const float* __restrict__ x,
                                                    const int* __restrict__ mask,
                                                    bf16* __restrict__ d) {
    size_t i = (size_t)blockIdx.x * 256 + threadIdx.x;  // ROWS_*96
    size_t row = i / KE_;
    int col = (int)(i % KE_);
    float v = 0.f;
    if (col < S_) v = x[row * S_ + col];
    else if (col < 2 * S_) v = (float)mask[row * S_ + (col - S_)];
    d[i] = (bf16)v;
}

// Wbig rows 0..1535: Wcomb[d,k] = sum_r dtw[d,r] * xpw[r,k]
__global__ __launch_bounds__(256) void wcomb_kernel(const float* __restrict__ dtw,
                                                    const float* __restrict__ xpw,
                                                    bf16* __restrict__ wbig) {
    int l = blockIdx.y;
    size_t idx = (size_t)blockIdx.x * 256 + threadIdx.x;  // 1536*1536
    int i = (int)(idx / DI_), j = (int)(idx % DI_);
    const float* dr = dtw + ((size_t)l * DI_ + i) * DTR_;
    const float* xr = xpw + (size_t)l * (DTR_ + 2 * N_) * DI_ + j;
    float acc = 0.f;
    #pragma unroll
    for (int r = 0; r < DTR_; r++) acc += dr[r] * xr[(size_t)r * DI_];
    wbig[(size_t)l * NP2A_ * DI_ + idx] = (bf16)acc;
}

__global__ __launch_bounds__(256) void wbig_bc_kernel(const float* __restrict__ xpw,
                                                      bf16* __restrict__ wbig) {
    int l = blockIdx.y;
    int idx = blockIdx.x * 256 + threadIdx.x;   // 128*1536
    int row = DI_ + idx / DI_, col = idx % DI_;
    float v = 0.f;
    if (row < NP2_) v = xpw[(size_t)l * (DTR_ + 2 * N_) * DI_ + (size_t)(DTR_ + row - DI_) * DI_ + col];
    wbig[(size_t)l * NP2A_ * DI_ + (size_t)row * DI_ + col] = (bf16)v;
}

__global__ __launch_bounds__(256) void sstat_kernel(const float* __restrict__ stat,
                                                    const float* __restrict__ static_w,
                                                    const float* __restrict__ static_b,
                                                    const float* __restrict__ emb_b,
                                                    float* __restrict__ sstat) {
    int i = blockIdx.x * 256 + threadIdx.x;  // B_*D_
    int d = i % D_, b = i / D_;
    float acc = emb_b[d] + static_b[d];
    const float* sw = static_w + (size_t)d * STATIC_;
    const float* sv = stat + (size_t)b * STATIC_;
    #pragma unroll
    for (int s = 0; s < STATIC_; s++) acc += sv[s] * sw[s];
    sstat[i] = acc;
}

__device__ __forceinline__ void block_reduce2_(float& a, float& b, float* sbuf) {
    #pragma unroll
    for (int off = 32; off > 0; off >>= 1) {
        a += __shfl_down(a, off, 64);
        b += __shfl_down(b, off, 64);
    }
    int lane = threadIdx.x & 63, wid = threadIdx.x >> 6;
    if (lane == 0) { sbuf[wid] = a; sbuf[4 + wid] = b; }
    __syncthreads();
    a = sbuf[0] + sbuf[1] + sbuf[2] + sbuf[3];
    b = sbuf[4] + sbuf[5] + sbuf[6] + sbuf[7];
}

__global__ __launch_bounds__(256) void ln_embed_kernel(const float* __restrict__ h_pre,
                                                       const float* __restrict__ sstat,
                                                       const float* __restrict__ ln_w,
                                                       const float* __restrict__ ln_b,
                                                       float* __restrict__ h) {
    int row = blockIdx.x, b = row / L_, tid = threadIdx.x;
    __shared__ float sbuf[8];
    float v[3], sum = 0.f, sq = 0.f;
    #pragma unroll
    for (int j = 0; j < 3; j++) {
        int d = tid + 256 * j;
        v[j] = h_pre[(size_t)row * D_ + d] + sstat[b * D_ + d];
        sum += v[j]; sq += v[j] * v[j];
    }
    block_reduce2_(sum, sq, sbuf);
    float mu = sum * (1.f / D_);
    float rstd = rsqrtf(sq * (1.f / D_) - mu * mu + 1e-5f);
    #pragma unroll
    for (int j = 0; j < 3; j++) {
        int d = tid + 256 * j;
        h[(size_t)row * D_ + d] = (v[j] - mu) * rstd * ln_w[d] + ln_b[d];
    }
}

__global__ __launch_bounds__(256) void rmsnorm_bf_kernel(const float* __restrict__ h,
                                                         const float* __restrict__ w,
                                                         bf16* __restrict__ out) {
    int row = blockIdx.x, tid = threadIdx.x;
    __shared__ float sbuf[8];
    float v[3], ss = 0.f, dummy = 0.f;
    #pragma unroll
    for (int j = 0; j < 3; j++) {
        v[j] = h[(size_t)row * D_ + tid + 256 * j];
        ss += v[j] * v[j];
    }
    block_reduce2_(ss, dummy, sbuf);
    float rstd = rsqrtf(ss * (1.f / D_) + 1e-5f);
    #pragma unroll
    for (int j = 0; j < 3; j++) {
        int d = tid + 256 * j;
        out[(size_t)row * D_ + d] = (bf16)(v[j] * rstd * w[d]);
    }
}

// conv K=4 + silu -> xc ; gate pack -> scanin[idx].y = pack(D*u*gz, gz)
__global__ __launch_bounds__(256) void conv_silu_kernel(const bf16* __restrict__ xzb,
                                                        const float* __restrict__ cw,
                                                        const float* __restrict__ cb,
                                                        const float* __restrict__ Dp,
                                                        bf16* __restrict__ xcb,
                                                        unsigned* __restrict__ scanw) {
    size_t idx = (size_t)blockIdx.x * 256 + threadIdx.x;   // CROWS_*DI_
    int d = (int)(idx % DI_);
    size_t row = idx / DI_;
    int t = (int)(row % L_);
    float acc = cb[d];
    const float* w = cw + d * 4;
    if (t >= 3) acc += w[0] * (float)xzb[(row - 3) * (2 * DI_) + d];
    if (t >= 2) acc += w[1] * (float)xzb[(row - 2) * (2 * DI_) + d];
    if (t >= 1) acc += w[2] * (float)xzb[(row - 1) * (2 * DI_) + d];
    acc += w[3] * (float)xzb[row * (2 * DI_) + d];
    float u = silu_(acc);
    xcb[idx] = (bf16)u;
    float z = (float)xzb[row * (2 * DI_) + DI_ + d];
    float gz = silu_(z);
    scanw[2 * idx + 1] = pack_bf2_(Dp[d] * u * gz, gz);
}

// ============== pipelined scan: double-buffered 16-deep register prefetch ==============
__device__ __forceinline__ void scan_load_(const uint2* __restrict__ pin,
                                           const float2* __restrict__ pBC,
                                           int t, uint2* inb, float2* bcb) {
    #pragma unroll
    for (int u = 0; u < UU_; u++) {
        int tt = t + u; tt = tt < L_ ? tt : L_ - 1;   // uniform clamp (scalar)
        inb[u] = pin[(size_t)tt * DI_];
        bcb[u] = pBC[(size_t)tt * 16];
    }
}

__device__ __forceinline__ void scan_compute_(const uint2* inb, const float2* bcb,
                                              float Av, float& h, int n,
                                              bf16* __restrict__ py, int t0) {
    #pragma unroll
    for (int u = 0; u < UU_; u++) {
        uint2 iv = inb[u];
        bf16x2 dv = __builtin_bit_cast(bf16x2, iv.x);
        float du = (float)dv.x, dtv = (float)dv.y;
        float2 bcv = bcb[u];
        float dA = __expf(dtv * Av);
        h = dA * h + du * bcv.x;
        float p = h * bcv.y;
        p += __shfl_xor(p, 1);
        p += __shfl_xor(p, 2);
        p += __shfl_xor(p, 4);
        p += __shfl_xor(p, 8);
        if (n == 0) {
            bf16x2 og = __builtin_bit_cast(bf16x2, iv.y);
            py[(size_t)(t0 + u) * DI_] = (bf16)(p * (float)og.y + (float)og.x);
        }
    }
}

__global__ __launch_bounds__(256) void scan3_kernel(const float* __restrict__ bc,
                                                    const uint2* __restrict__ scanin,
                                                    const float* __restrict__ A_log,
                                                    bf16* __restrict__ yb) {
    int tid = threadIdx.x;
    int n = tid & 15;
    int d = blockIdx.x * 16 + (tid >> 4);
    int b = blockIdx.y;
    float Av = -__expf(A_log[(size_t)d * N_ + n]);
    float h = 0.f;
    size_t rbase = (size_t)b * L_;
    const uint2*  pin = scanin + rbase * DI_ + d;
    const float2* pBC = (const float2*)bc + rbase * 16 + n;
    bf16*         py  = yb + rbase * DI_ + d;

    uint2  inA[UU_], inB[UU_];
    float2 bcA[UU_], bcB[UU_];
    scan_load_(pin, pBC, 0, inA, bcA);
    for (int t0 = 0; t0 < L_; t0 += 2 * UU_) {
        scan_load_(pin, pBC, t0 + UU_, inB, bcB);
        scan_compute_(inA, bcA, Av, h, n, py, t0);
        scan_load_(pin, pBC, t0 + 2 * UU_, inA, bcA);
        scan_compute_(inB, bcB, Av, h, n, py, t0 + UU_);
    }
}

extern "C" void kernel_launch(void* const* d_in, const int* in_sizes, int n_in,
                              void* d_out, int out_size, void* d_ws, size_t ws_size,
                              hipStream_t stream) {
    const float* x        = (const float*)d_in[0];
    const float* stat     = (const float*)d_in[1];
    const int*   mask     = (const int*)d_in[3];
    const float* emb_w    = (const float*)d_in[5];
    const float* emb_b    = (const float*)d_in[6];
    const float* static_w = (const float*)d_in[7];
    const float* static_b = (const float*)d_in[8];
    const float* ln_w     = (const float*)d_in[9];
    const float* ln_b     = (const float*)d_in[10];
    const float* norm_w   = (const float*)d_in[11];
    const float* in_proj_w  = (const float*)d_in[12];
    const float* conv_w   = (const float*)d_in[13];
    const float* conv_b   = (const float*)d_in[14];
    const float* x_proj_w = (const float*)d_in[15];
    const float* dt_proj_w= (const float*)d_in[16];
    const float* dt_proj_b= (const float*)d_in[17];
    const float* A_log    = (const float*)d_in[18];
    const float* D_param  = (const float*)d_in[19];
    const float* out_proj_w = (const float*)d_in[20];
    const float* norm_f_w = (const float*)d_in[21];
    const float* lm_head_w= (const float*)d_in[22];
    float* out = (float*)d_out;

    // ---- workspace layout (bytes), total ~211 MB ----
    char* p = (char*)d_ws;
    float*    h      = (float*)p;         p += (size_t)ROWS_ * D_ * 4;          // 50.3 MB
    bf16*     hn_bf  = (bf16*)p;          p += (size_t)CROWS_ * D_ * 2;         // 6.3
    char*     xz_region = p;                                                    // h_pre alias start
    bf16*     xz_bf  = (bf16*)p;          p += (size_t)CROWS_ * 2 * DI_ * 2;    // 25.2
    bf16*     xc_bf  = (bf16*)p;          p += (size_t)CROWS_ * DI_ * 2;        // 12.6
    unsigned* scanw  = (unsigned*)p;      p += (size_t)CROWS_ * DI_ * 8;        // 50.3 (uint2)
    float*    bc     = (float*)p;         p += (size_t)CROWS_ * 32 * 4;         // 0.5
    bf16*     y_bf   = (bf16*)p;          p += (size_t)CROWS_ * DI_ * 2;        // 12.6
    bf16*     inw_bf = (bf16*)p;          p += (size_t)NL_ * 2 * DI_ * D_ * 2;  // 18.9
    bf16*     outw_bf= (bf16*)p;          p += (size_t)NL_ * D_ * DI_ * 2;      // 9.4
    bf16*     wbig   = (bf16*)p;          p += (size_t)NL_ * NP2A_ * DI_ * 2;   // 20.4
    bf16*     lmw_bf = (bf16*)p;          p += (size_t)128 * D_ * 2;
    bf16*     embw_bf= (bf16*)p;          p += (size_t)D_ * KE_ * 2;
    bf16*     feats  = (bf16*)p;          p += (size_t)ROWS_ * KE_ * 2;         // 3.1
    float*    sstat  = (float*)p;         p += (size_t)B_ * D_ * 4;
    float*    h_pre  = (float*)xz_region; // 50.3 MB alias over xz/xc/scanw (dead then)

    // ---- weight prep ----
    cast_f2b_kernel<<<(NL_ * 2 * DI_ * D_) / 256, 256, 0, stream>>>(in_proj_w, inw_bf);
    cast_f2b_kernel<<<(NL_ * D_ * DI_) / 256, 256, 0, stream>>>(out_proj_w, outw_bf);
    pad_lm_kernel<<<(128 * D_) / 256, 256, 0, stream>>>(lm_head_w, lmw_bf);
    pad_embw_kernel<<<(D_ * KE_) / 256, 256, 0, stream>>>(emb_w, embw_bf);
    feats_kernel<<<(ROWS_ * KE_) / 256, 256, 0, stream>>>(x, mask, feats);
    dim3 gwc((DI_ * DI_) / 256, NL_);
    wcomb_kernel<<<gwc, 256, 0, stream>>>(dt_proj_w, x_proj_w, wbig);
    dim3 gbc((128 * DI_) / 256, NL_);
    wbig_bc_kernel<<<gbc, 256, 0, stream>>>(x_proj_w, wbig);
    sstat_kernel<<<(B_ * D_) / 256, 256, 0, stream>>>(stat, static_w, static_b, emb_b, sstat);

    // ---- embed + LN ----
    dim3 ge(D_ / 128, ROWS_ / 128);
    gemm_mfma<0><<<ge, 256, 0, stream>>>(feats, embw_bf, nullptr, h_pre, D_, KE_,
                                         nullptr, nullptr, nullptr);
    ln_embed_kernel<<<ROWS_, 256, 0, stream>>>(h_pre, sstat, ln_w, ln_b, h);

    // ---- layers ----
    for (int l = 0; l < NL_; l++) {
        for (int c = 0; c < NCH_; c++) {
            float* hc = h + (size_t)c * CROWS_ * D_;

            rmsnorm_bf_kernel<<<CROWS_, 256, 0, stream>>>(hc, norm_w + (size_t)l * D_, hn_bf);

            dim3 g1((2 * DI_) / 128, CROWS_ / 128);
            gemm_mfma<1><<<g1, 256, 0, stream>>>(hn_bf, inw_bf + (size_t)l * 2 * DI_ * D_,
                                                 nullptr, xz_bf, 2 * DI_, D_,
                                                 nullptr, nullptr, nullptr);

            conv_silu_kernel<<<(CROWS_ * DI_) / 256, 256, 0, stream>>>(
                xz_bf, conv_w + (size_t)l * DI_ * 4, conv_b + (size_t)l * DI_,
                D_param + (size_t)l * DI_, xc_bf, scanw);

            dim3 g2(NP2A_ / 128, CROWS_ / 128);
            gemm_mfma<2><<<g2, 256, 0, stream>>>(xc_bf, wbig + (size_t)l * NP2A_ * DI_,
                                                 nullptr, nullptr, NP2_, DI_,
                                                 dt_proj_b + (size_t)l * DI_, scanw, bc);

            dim3 gs(DI_ / 16, CB_);
            scan3_kernel<<<gs, 256, 0, stream>>>(bc, (const uint2*)scanw,
                                                 A_log + (size_t)l * DI_ * N_, y_bf);

            dim3 g3(D_ / 128, CROWS_ / 128);
            gemm_mfma<0><<<g3, 256, 0, stream>>>(y_bf, outw_bf + (size_t)l * D_ * DI_,
                                                 hc, hc, D_, DI_,
                                                 nullptr, nullptr, nullptr);
        }
    }

    // ---- final rmsnorm + lm_head ----
    for (int c = 0; c < NCH_; c++) {
        float* hc = h + (size_t)c * CROWS_ * D_;
        rmsnorm_bf_kernel<<<CROWS_, 256, 0, stream>>>(hc, norm_f_w, hn_bf);
        dim3 glm(1, CROWS_ / 128);
        gemm_mfma<0><<<glm, 256, 0, stream>>>(hn_bf, lmw_bf, nullptr,
                                              out + (size_t)c * CROWS_ * V_, V_, D_,
                                              nullptr, nullptr, nullptr);
    }
}

// Round 8
// 5188.290 us; speedup vs baseline: 3.5757x; 1.0606x over previous
//
#include <hip/hip_runtime.h>
#include <math.h>

#define B_ 32
#define L_ 512
#define S_ 37
#define STATIC_ 8
#define D_ 768
#define DI_ 1536
#define N_ 16
#define DTR_ 48
#define NL_ 4
#define V_ 32
#define ROWS_ (B_*L_)      // 16384
#define CB_ 8              // batch chunk
#define CROWS_ (CB_*L_)    // 4096
#define NCH_ (B_/CB_)      // 4
#define NP2_ 1568          // dt_pre(1536) + B(16) + C(16)
#define NP2A_ 1664         // padded to 13*128
#define KE_ 96             // padded embed K (74 -> 96)
#define UU_ 16             // scan software-pipeline depth

typedef __bf16 bf16;
typedef __bf16 bf16x8 __attribute__((ext_vector_type(8)));
typedef __bf16 bf16x2 __attribute__((ext_vector_type(2)));
typedef float f32x4 __attribute__((ext_vector_type(4)));

typedef __attribute__((address_space(3))) void lds_void;
typedef __attribute__((address_space(1))) const void gmem_void;

__device__ __forceinline__ void gld16(const void* g, void* l) {
    __builtin_amdgcn_global_load_lds((gmem_void*)g, (lds_void*)l, 16, 0, 0);
}

__device__ __forceinline__ float silu_(float x) { return x / (1.f + __expf(-x)); }
__device__ __forceinline__ float softplus_(float x) {
    return fmaxf(x, 0.f) + __logf(1.f + __expf(-fabsf(x)));
}
__device__ __forceinline__ unsigned pack_bf2_(float a, float b) {
    bf16x2 v{(bf16)a, (bf16)b};
    return __builtin_bit_cast(unsigned, v);
}
// cross-lane add via DPP (VALU pipe, no LDS): CTRL = quad_perm / row_ror (constexpr)
template<int CTRL>
__device__ __forceinline__ float dpp_add_(float p) {
    int vi = __builtin_amdgcn_update_dpp(0, __builtin_bit_cast(int, p),
                                         CTRL, 0xF, 0xF, true);
    return p + __builtin_bit_cast(float, vi);
}

// ================= bf16 MFMA GEMM: C[M,*] = A[M,K] @ W[Nalloc,K]^T =================
// MODE 0: f32 out (+addsrc); MODE 1: bf16 out;
// MODE 2: scan-prep: n<DI_ -> scanin[m*DI_+n].x = pack(du,dtv); DI_<=n<NP2_ -> interleaved bc
template<int MODE>
__global__ __launch_bounds__(256) void gemm_mfma(
    const bf16* __restrict__ A, const bf16* __restrict__ W,
    const float* __restrict__ addsrc, void* __restrict__ Cv,
    int Nstore, int K,
    const float* __restrict__ dt_bias, unsigned* __restrict__ scanw,
    float* __restrict__ bc)
{
    __shared__ bf16 As[128 * 32];
    __shared__ bf16 Bs[128 * 32];
    const int tid = threadIdx.x;
    const int m0 = blockIdx.y * 128, n0 = blockIdx.x * 128;

    f32x4 acc[4][4];
    #pragma unroll
    for (int i = 0; i < 4; i++)
        #pragma unroll
        for (int j = 0; j < 4; j++)
            acc[i][j] = f32x4{0.f, 0.f, 0.f, 0.f};

    const int srow = tid >> 2, spart = tid & 3;
    const bf16* ag = A + (size_t)(m0 + srow) * K + spart * 8;
    const bf16* wg = W + (size_t)(n0 + srow) * K + spart * 8;
    char* lA = (char*)As + tid * 16;
    char* lB = (char*)Bs + tid * 16;

    const int lane = tid & 63, wv = tid >> 6;
    const int wr = wv >> 1, wc = wv & 1;
    const int colL = lane & 15, quad = lane >> 4;
    const bf16* aRd = As + (wr * 64 + colL) * 32 + quad * 8;
    const bf16* bRd = Bs + (wc * 64 + colL) * 32 + quad * 8;

    for (int kt = 0; kt < K; kt += 32) {
        gld16(ag + kt, lA);
        gld16(ag + kt + (size_t)64 * K, lA + 4096);
        gld16(wg + kt, lB);
        gld16(wg + kt + (size_t)64 * K, lB + 4096);
        __syncthreads();
        bf16x8 fa[4], fb[4];
        #pragma unroll
        for (int i = 0; i < 4; i++) fa[i] = *(const bf16x8*)(aRd + i * 16 * 32);
        #pragma unroll
        for (int j = 0; j < 4; j++) fb[j] = *(const bf16x8*)(bRd + j * 16 * 32);
        #pragma unroll
        for (int i = 0; i < 4; i++)
            #pragma unroll
            for (int j = 0; j < 4; j++)
                acc[i][j] = __builtin_amdgcn_mfma_f32_16x16x32_bf16(fa[i], fb[j], acc[i][j], 0, 0, 0);
        __syncthreads();
    }

    float* Cf = (float*)Cv;
    bf16*  Cb = (bf16*)Cv;
    #pragma unroll
    for (int i = 0; i < 4; i++) {
        #pragma unroll
        for (int j = 0; j < 4; j++) {
            int n = n0 + wc * 64 + j * 16 + colL;
            #pragma unroll
            for (int r = 0; r < 4; r++) {
                int m = m0 + wr * 64 + i * 16 + quad * 4 + r;
                float v = acc[i][j][r];
                if (MODE == 2) {
                    if (n < DI_) {
                        float dtv = softplus_(v + dt_bias[n]);
                        float u = (float)A[(size_t)m * DI_ + n];
                        scanw[2 * ((size_t)m * DI_ + n)] = pack_bf2_(dtv * u, dtv);
                    } else if (n < NP2_) {
                        int jj = n - DI_;
                        int pos = (jj < 16) ? (2 * jj) : (2 * (jj - 16) + 1);
                        bc[(size_t)m * 32 + pos] = v;
                    }
                } else if (n < Nstore) {
                    if (addsrc) v += addsrc[(size_t)m * Nstore + n];
                    if (MODE == 1) Cb[(size_t)m * Nstore + n] = (bf16)v;
                    else           Cf[(size_t)m * Nstore + n] = v;
                }
            }
        }
    }
}

// ================= small prep kernels =================
__global__ __launch_bounds__(256) void cast_f2b_kernel(const float* __restrict__ s,
                                                       bf16* __restrict__ d) {
    size_t i = (size_t)blockIdx.x * 256 + threadIdx.x;
    d[i] = (bf16)s[i];
}

__global__ __launch_bounds__(256) void pad_lm_kernel(const float* __restrict__ s, bf16* __restrict__ d) {
    int i = blockIdx.x * 256 + threadIdx.x;     // 128*768
    int row = i / D_;
    d[i] = (row < V_) ? (bf16)s[i] : (bf16)0.f;
}

__global__ __launch_bounds__(256) void pad_embw_kernel(const float* __restrict__ s, bf16* __restrict__ d) {
    int i = blockIdx.x * 256 + threadIdx.x;     // 768*96
    int row = i / KE_, col = i % KE_;
    d[i] = (col < 2 * S_) ? (bf16)s[row * 2 * S_ + col] : (bf16)0.f;
}

__global__ __launch_bounds__(256) void feats_kernel(const float* __restrict__ x,
                                                    const int* __restrict__ mask,
                                                    bf16* __restrict__ d) {
    size_t i = (size_t)blockIdx.x * 256 + threadIdx.x;  // ROWS_*96
    size_t row = i / KE_;
    int col = (int)(i % KE_);
    float v = 0.f;
    if (col < S_) v = x[row * S_ + col];
    else if (col < 2 * S_) v = (float)mask[row * S_ + (col - S_)];
    d[i] = (bf16)v;
}

// Wbig rows 0..1535: Wcomb[d,k] = sum_r dtw[d,r] * xpw[r,k]
__global__ __launch_bounds__(256) void wcomb_kernel(const float* __restrict__ dtw,
                                                    const float* __restrict__ xpw,
                                                    bf16* __restrict__ wbig) {
    int l = blockIdx.y;
    size_t idx = (size_t)blockIdx.x * 256 + threadIdx.x;  // 1536*1536
    int i = (int)(idx / DI_), j = (int)(idx % DI_);
    const float* dr = dtw + ((size_t)l * DI_ + i) * DTR_;
    const float* xr = xpw + (size_t)l * (DTR_ + 2 * N_) * DI_ + j;
    float acc = 0.f;
    #pragma unroll
    for (int r = 0; r < DTR_; r++) acc += dr[r] * xr[(size_t)r * DI_];
    wbig[(size_t)l * NP2A_ * DI_ + idx] = (bf16)acc;
}

__global__ __launch_bounds__(256) void wbig_bc_kernel(const float* __restrict__ xpw,
                                                      bf16* __restrict__ wbig) {
    int l = blockIdx.y;
    int idx = blockIdx.x * 256 + threadIdx.x;   // 128*1536
    int row = DI_ + idx / DI_, col = idx % DI_;
    float v = 0.f;
    if (row < NP2_) v = xpw[(size_t)l * (DTR_ + 2 * N_) * DI_ + (size_t)(DTR_ + row - DI_) * DI_ + col];
    wbig[(size_t)l * NP2A_ * DI_ + (size_t)row * DI_ + col] = (bf16)v;
}

__global__ __launch_bounds__(256) void sstat_kernel(const float* __restrict__ stat,
                                                    const float* __restrict__ static_w,
                                                    const float* __restrict__ static_b,
                                                    const float* __restrict__ emb_b,
                                                    float* __restrict__ sstat) {
    int i = blockIdx.x * 256 + threadIdx.x;  // B_*D_
    int d = i % D_, b = i / D_;
    float acc = emb_b[d] + static_b[d];
    const float* sw = static_w + (size_t)d * STATIC_;
    const float* sv = stat + (size_t)b * STATIC_;
    #pragma unroll
    for (int s = 0; s < STATIC_; s++) acc += sv[s] * sw[s];
    sstat[i] = acc;
}

__device__ __forceinline__ void block_reduce2_(float& a, float& b, float* sbuf) {
    #pragma unroll
    for (int off = 32; off > 0; off >>= 1) {
        a += __shfl_down(a, off, 64);
        b += __shfl_down(b, off, 64);
    }
    int lane = threadIdx.x & 63, wid = threadIdx.x >> 6;
    if (lane == 0) { sbuf[wid] = a; sbuf[4 + wid] = b; }
    __syncthreads();
    a = sbuf[0] + sbuf[1] + sbuf[2] + sbuf[3];
    b = sbuf[4] + sbuf[5] + sbuf[6] + sbuf[7];
}

__global__ __launch_bounds__(256) void ln_embed_kernel(const float* __restrict__ h_pre,
                                                       const float* __restrict__ sstat,
                                                       const float* __restrict__ ln_w,
                                                       const float* __restrict__ ln_b,
                                                       float* __restrict__ h) {
    int row = blockIdx.x, b = row / L_, tid = threadIdx.x;
    __shared__ float sbuf[8];
    float v[3], sum = 0.f, sq = 0.f;
    #pragma unroll
    for (int j = 0; j < 3; j++) {
        int d = tid + 256 * j;
        v[j] = h_pre[(size_t)row * D_ + d] + sstat[b * D_ + d];
        sum += v[j]; sq += v[j] * v[j];
    }
    block_reduce2_(sum, sq, sbuf);
    float mu = sum * (1.f / D_);
    float rstd = rsqrtf(sq * (1.f / D_) - mu * mu + 1e-5f);
    #pragma unroll
    for (int j = 0; j < 3; j++) {
        int d = tid + 256 * j;
        h[(size_t)row * D_ + d] = (v[j] - mu) * rstd * ln_w[d] + ln_b[d];
    }
}

__global__ __launch_bounds__(256) void rmsnorm_bf_kernel(const float* __restrict__ h,
                                                         const float* __restrict__ w,
                                                         bf16* __restrict__ out) {
    int row = blockIdx.x, tid = threadIdx.x;
    __shared__ float sbuf[8];
    float v[3], ss = 0.f, dummy = 0.f;
    #pragma unroll
    for (int j = 0; j < 3; j++) {
        v[j] = h[(size_t)row * D_ + tid + 256 * j];
        ss += v[j] * v[j];
    }
    block_reduce2_(ss, dummy, sbuf);
    float rstd = rsqrtf(ss * (1.f / D_) + 1e-5f);
    #pragma unroll
    for (int j = 0; j < 3; j++) {
        int d = tid + 256 * j;
        out[(size_t)row * D_ + d] = (bf16)(v[j] * rstd * w[d]);
    }
}

// conv K=4 + silu -> xc ; gate pack -> scanin[idx].y = pack(D*u*gz, gz)
__global__ __launch_bounds__(256) void conv_silu_kernel(const bf16* __restrict__ xzb,
                                                        const float* __restrict__ cw,
                                                        const float* __restrict__ cb,
                                                        const float* __restrict__ Dp,
                                                        bf16* __restrict__ xcb,
                                                        unsigned* __restrict__ scanw) {
    size_t idx = (size_t)blockIdx.x * 256 + threadIdx.x;   // CROWS_*DI_
    int d = (int)(idx % DI_);
    size_t row = idx / DI_;
    int t = (int)(row % L_);
    float acc = cb[d];
    const float* w = cw + d * 4;
    if (t >= 3) acc += w[0] * (float)xzb[(row - 3) * (2 * DI_) + d];
    if (t >= 2) acc += w[1] * (float)xzb[(row - 2) * (2 * DI_) + d];
    if (t >= 1) acc += w[2] * (float)xzb[(row - 1) * (2 * DI_) + d];
    acc += w[3] * (float)xzb[row * (2 * DI_) + d];
    float u = silu_(acc);
    xcb[idx] = (bf16)u;
    float z = (float)xzb[row * (2 * DI_) + DI_ + d];
    float gz = silu_(z);
    scanw[2 * idx + 1] = pack_bf2_(Dp[d] * u * gz, gz);
}

// ============== pipelined scan: 16-deep register prefetch + DPP reduction ==============
__device__ __forceinline__ void scan_load_(const uint2* __restrict__ pin,
                                           const float2* __restrict__ pBC,
                                           int t, uint2* inb, float2* bcb) {
    #pragma unroll
    for (int u = 0; u < UU_; u++) {
        int tt = t + u; tt = tt < L_ ? tt : L_ - 1;   // uniform clamp (scalar)
        inb[u] = pin[(size_t)tt * DI_];
        bcb[u] = pBC[(size_t)tt * 16];
    }
}

__device__ __forceinline__ void scan_compute_(const uint2* inb, const float2* bcb,
                                              float AvL, float& h, int n,
                                              bf16* __restrict__ py, int t0) {
    #pragma unroll
    for (int u = 0; u < UU_; u++) {
        uint2 iv = inb[u];
        bf16x2 dv = __builtin_bit_cast(bf16x2, iv.x);
        float du = (float)dv.x, dtv = (float)dv.y;
        float2 bcv = bcb[u];
        float dA = __builtin_amdgcn_exp2f(dtv * AvL);
        h = dA * h + du * bcv.x;
        float p = h * bcv.y;
        // reduce over the 16-lane row: quad xor1, xor2, then row_ror 4, 8 — all VALU
        p = dpp_add_<0xB1>(p);    // quad_perm(1,0,3,2)
        p = dpp_add_<0x4E>(p);    // quad_perm(2,3,0,1)
        p = dpp_add_<0x124>(p);   // row_ror:4
        p = dpp_add_<0x128>(p);   // row_ror:8
        if (n == 0) {
            bf16x2 og = __builtin_bit_cast(bf16x2, iv.y);
            py[(size_t)(t0 + u) * DI_] = (bf16)(p * (float)og.y + (float)og.x);
        }
    }
}

__global__ __launch_bounds__(256) void scan3_kernel(const float* __restrict__ bc,
                                                    const uint2* __restrict__ scanin,
                                                    const float* __restrict__ A_log,
                                                    bf16* __restrict__ yb) {
    int tid = threadIdx.x;
    int n = tid & 15;
    int d = blockIdx.x * 16 + (tid >> 4);
    int b = blockIdx.y;
    float AvL = -__expf(A_log[(size_t)d * N_ + n]) * 1.44269504f;  // fold log2(e)
    float h = 0.f;
    size_t rbase = (size_t)b * L_;
    const uint2*  pin = scanin + rbase * DI_ + d;
    const float2* pBC = (const float2*)bc + rbase * 16 + n;
    bf16*         py  = yb + rbase * DI_ + d;

    uint2  inA[UU_], inB[UU_];
    float2 bcA[UU_], bcB[UU_];
    scan_load_(pin, pBC, 0, inA, bcA);
    for (int t0 = 0; t0 < L_; t0 += 2 * UU_) {
        scan_load_(pin, pBC, t0 + UU_, inB, bcB);
        scan_compute_(inA, bcA, AvL, h, n, py, t0);
        scan_load_(pin, pBC, t0 + 2 * UU_, inA, bcA);
        scan_compute_(inB, bcB, AvL, h, n, py, t0 + UU_);
    }
}

extern "C" void kernel_launch(void* const* d_in, const int* in_sizes, int n_in,
                              void* d_out, int out_size, void* d_ws, size_t ws_size,
                              hipStream_t stream) {
    const float* x        = (const float*)d_in[0];
    const float* stat     = (const float*)d_in[1];
    const int*   mask     = (const int*)d_in[3];
    const float* emb_w    = (const float*)d_in[5];
    const float* emb_b    = (const float*)d_in[6];
    const float* static_w = (const float*)d_in[7];
    const float* static_b = (const float*)d_in[8];
    const float* ln_w     = (const float*)d_in[9];
    const float* ln_b     = (const float*)d_in[10];
    const float* norm_w   = (const float*)d_in[11];
    const float* in_proj_w  = (const float*)d_in[12];
    const float* conv_w   = (const float*)d_in[13];
    const float* conv_b   = (const float*)d_in[14];
    const float* x_proj_w = (const float*)d_in[15];
    const float* dt_proj_w= (const float*)d_in[16];
    const float* dt_proj_b= (const float*)d_in[17];
    const float* A_log    = (const float*)d_in[18];
    const float* D_param  = (const float*)d_in[19];
    const float* out_proj_w = (const float*)d_in[20];
    const float* norm_f_w = (const float*)d_in[21];
    const float* lm_head_w= (const float*)d_in[22];
    float* out = (float*)d_out;

    // ---- workspace layout (bytes), total ~211 MB ----
    char* p = (char*)d_ws;
    float*    h      = (float*)p;         p += (size_t)ROWS_ * D_ * 4;          // 50.3 MB
    bf16*     hn_bf  = (bf16*)p;          p += (size_t)CROWS_ * D_ * 2;         // 6.3
    char*     xz_region = p;                                                    // h_pre alias start
    bf16*     xz_bf  = (bf16*)p;          p += (size_t)CROWS_ * 2 * DI_ * 2;    // 25.2
    bf16*     xc_bf  = (bf16*)p;          p += (size_t)CROWS_ * DI_ * 2;        // 12.6
    unsigned* scanw  = (unsigned*)p;      p += (size_t)CROWS_ * DI_ * 8;        // 50.3 (uint2)
    float*    bc     = (float*)p;         p += (size_t)CROWS_ * 32 * 4;         // 0.5
    bf16*     y_bf   = (bf16*)p;          p += (size_t)CROWS_ * DI_ * 2;        // 12.6
    bf16*     inw_bf = (bf16*)p;          p += (size_t)NL_ * 2 * DI_ * D_ * 2;  // 18.9
    bf16*     outw_bf= (bf16*)p;          p += (size_t)NL_ * D_ * DI_ * 2;      // 9.4
    bf16*     wbig   = (bf16*)p;          p += (size_t)NL_ * NP2A_ * DI_ * 2;   // 20.4
    bf16*     lmw_bf = (bf16*)p;          p += (size_t)128 * D_ * 2;
    bf16*     embw_bf= (bf16*)p;          p += (size_t)D_ * KE_ * 2;
    bf16*     feats  = (bf16*)p;          p += (size_t)ROWS_ * KE_ * 2;         // 3.1
    float*    sstat  = (float*)p;         p += (size_t)B_ * D_ * 4;
    float*    h_pre  = (float*)xz_region; // 50.3 MB alias over xz/xc/scanw (dead then)

    // ---- weight prep ----
    cast_f2b_kernel<<<(NL_ * 2 * DI_ * D_) / 256, 256, 0, stream>>>(in_proj_w, inw_bf);
    cast_f2b_kernel<<<(NL_ * D_ * DI_) / 256, 256, 0, stream>>>(out_proj_w, outw_bf);
    pad_lm_kernel<<<(128 * D_) / 256, 256, 0, stream>>>(lm_head_w, lmw_bf);
    pad_embw_kernel<<<(D_ * KE_) / 256, 256, 0, stream>>>(emb_w, embw_bf);
    feats_kernel<<<(ROWS_ * KE_) / 256, 256, 0, stream>>>(x, mask, feats);
    dim3 gwc((DI_ * DI_) / 256, NL_);
    wcomb_kernel<<<gwc, 256, 0, stream>>>(dt_proj_w, x_proj_w, wbig);
    dim3 gbc((128 * DI_) / 256, NL_);
    wbig_bc_kernel<<<gbc, 256, 0, stream>>>(x_proj_w, wbig);
    sstat_kernel<<<(B_ * D_) / 256, 256, 0, stream>>>(stat, static_w, static_b, emb_b, sstat);

    // ---- embed + LN ----
    dim3 ge(D_ / 128, ROWS_ / 128);
    gemm_mfma<0><<<ge, 256, 0, stream>>>(feats, embw_bf, nullptr, h_pre, D_, KE_,
                                         nullptr, nullptr, nullptr);
    ln_embed_kernel<<<ROWS_, 256, 0, stream>>>(h_pre, sstat, ln_w, ln_b, h);

    // ---- layers ----
    for (int l = 0; l < NL_; l++) {
        for (int c = 0; c < NCH_; c++) {
            float* hc = h + (size_t)c * CROWS_ * D_;

            rmsnorm_bf_kernel<<<CROWS_, 256, 0, stream>>>(hc, norm_w + (size_t)l * D_, hn_bf);

            dim3 g1((2 * DI_) / 128, CROWS_ / 128);
            gemm_mfma<1><<<g1, 256, 0, stream>>>(hn_bf, inw_bf + (size_t)l * 2 * DI_ * D_,
                                                 nullptr, xz_bf, 2 * DI_, D_,
                                                 nullptr, nullptr, nullptr);

            conv_silu_kernel<<<(CROWS_ * DI_) / 256, 256, 0, stream>>>(
                xz_bf, conv_w + (size_t)l * DI_ * 4, conv_b + (size_t)l * DI_,
                D_param + (size_t)l * DI_, xc_bf, scanw);

            dim3 g2(NP2A_ / 128, CROWS_ / 128);
            gemm_mfma<2><<<g2, 256, 0, stream>>>(xc_bf, wbig + (size_t)l * NP2A_ * DI_,
                                                 nullptr, nullptr, NP2_, DI_,
                                                 dt_proj_b + (size_t)l * DI_, scanw, bc);

            dim3 gs(DI_ / 16, CB_);
            scan3_kernel<<<gs, 256, 0, stream>>>(bc, (const uint2*)scanw,
                                                 A_log + (size_t)l * DI_ * N_, y_bf);

            dim3 g3(D_ / 128, CROWS_ / 128);
            gemm_mfma<0><<<g3, 256, 0, stream>>>(y_bf, outw_bf + (size_t)l * D_ * DI_,
                                                 hc, hc, D_, DI_,
                                                 nullptr, nullptr, nullptr);
        }
    }

    // ---- final rmsnorm + lm_head ----
    for (int c = 0; c < NCH_; c++) {
        float* hc = h + (size_t)c * CROWS_ * D_;
        rmsnorm_bf_kernel<<<CROWS_, 256, 0, stream>>>(hc, norm_f_w, hn_bf);
        dim3 glm(1, CROWS_ / 128);
        gemm_mfma<0><<<glm, 256, 0, stream>>>(hn_bf, lmw_bf, nullptr,
                                              out + (size_t)c * CROWS_ * V_, V_, D_,
                                              nullptr, nullptr, nullptr);
    }
}